// Round 9
// baseline (379.513 us; speedup 1.0000x reference)
//
#include <hip/hip_runtime.h>
#include <math.h>

// N=100000 nodes, E=1600000 edges, HID=64, C=2, fp32.
// Hard-won constraints (R2-R23):
//  * FULLY-unrolled global-weight loads -> VGPR hoist -> spill (R2/R3);
//    #pragma unroll 2 bounds in-flight loads.
//  * 512-thread blocks unusable (VGPR cap 128 -> spill). 256 threads only.
//  * Random 4B scatter = 64B-line write amplification; fixed by LDS-staged
//    bucket sort (R13).
//  * R16: k_gather packed fp32 (v_pk_fma_f32), LDS transpose epilogue
//    reduce, 32-bit gather offsets. 98.7 -> <86us.
//  * R17: k_mlp per-wave 16-row tile, 4x4/thread, weights streamed from
//    global/L1, barrier-free (lgkmcnt fences only). 87 -> <73us.
//  * R18: k_gather 2 nodes/wave + padded LDS transpose.
//  * R19 FAILED: k_epi FULL global-weight streaming + no tile loop:
//    70->95us. LDS weights + tile-loop amortization is the k_epi way.
//  * R20: packed fp32 in k_epi/k_mlp GEMM cores -> both <68us. 426->398.
//  * R21 FAILED: k_gather 32-row register batching: occupancy 62->29%,
//    68->85us. k_gather pinned at ~3.5TB/s random-gather BW. REVERTED.
//  * R22: k_bscatter2 wave-striped bucket drain: 398->374.6.
//  * R23: SCT 6272 (256 tiles), packed u32 pairs, fill3 LDS staging,
//    memset for zero: 374.6->370.5. CSR chain now a minor term.
//  * R24 (this round): k_epi was 2 blocks/CU (LDS 68.6KB, occ 18.5%).
//    (a) stream ONLY wx from global/L1 (packed, unroll 2; W0/W1 stay in
//    LDS, tile loop kept -- unlike R19's failed full-streaming): LDS
//    -> ~51.5KB -> 3 blocks/CU. (b) merge W0/W1 GEMMs: one pass reads
//    each A float4 once, feeds both acc sets (A-tile ds_reads halved).
//    Per-output k-order preserved -> bit-identical.

#define SCT 6272     // edges per scatter tile: 256 tiles exactly
#define F3CAP 12288  // fill3 LDS staging capacity (mean bucket 8163, sd~90)

typedef float v2f __attribute__((ext_vector_type(2)));

__device__ __forceinline__ v2f v2fma(v2f a, v2f b, v2f c) {
#if __has_builtin(__builtin_elementwise_fma)
    return __builtin_elementwise_fma(a, b, c);
#else
    v2f r; r.x = fmaf(a.x, b.x, c.x); r.y = fmaf(a.y, b.y, c.y); return r;
#endif
}

// wave-level LDS fence: orders compiler memory ops + drains DS queue.
__device__ __forceinline__ void lds_fence() {
    asm volatile("s_waitcnt lgkmcnt(0)" ::: "memory");
}

__device__ __forceinline__ float fast_tanh(float x) {
    x = fminf(fmaxf(x, -15.f), 15.f);
    float e = __expf(2.f * x);
    return (e - 1.f) * __frcp_rn(e + 1.f);
}

// 256 threads: stage 32 rows x 64 cols (8 floats/thread) -- used by k_epi
__device__ __forceinline__ void load_rows32(const float* __restrict__ src, int row0, int n,
                                            float (*dst)[68], int t)
{
    int e = t * 8;
    int r = e >> 6, i = e & 63;
    int grow = row0 + r;
    float4 v0 = make_float4(0.f, 0.f, 0.f, 0.f), v1 = v0;
    if (grow < n) {
        const float* p = src + (size_t)grow * 64 + i;
        v0 = *(const float4*)p;
        v1 = *(const float4*)(p + 4);
    }
    *(float4*)&dst[r][i]     = v0;
    *(float4*)&dst[r][i + 4] = v1;
}

// ---- R24 packed core, weights streamed from GLOBAL/L1 (k_epi wx):
// 2 rows x 4 cols/thread; unroll 2 bounds in-flight loads (R2/R3). ----
__device__ __forceinline__ void gemm_gw_pk(const float (*in)[68], const float* __restrict__ w,
                                           const float* b, int rg, int cg,
                                           float (&o0)[4], float (&o1)[4])
{
    float bb0 = b[4*cg], bb1 = b[4*cg+1], bb2 = b[4*cg+2], bb3 = b[4*cg+3];
    v2f acc0a = {bb0, bb1}, acc0b = {bb2, bb3};
    v2f acc1a = acc0a, acc1b = acc0b;
    const int r0 = 2 * rg, r1 = 2 * rg + 1;
    const float* wp = w + 4 * cg;
#pragma unroll 2
    for (int i = 0; i < 64; i += 4) {
        float4 a0 = *(const float4*)&in[r0][i];
        float4 a1 = *(const float4*)&in[r1][i];
        v2f q0a = *(const v2f*)(wp + (i + 0) * 64), q0b = *(const v2f*)(wp + (i + 0) * 64 + 2);
        v2f q1a = *(const v2f*)(wp + (i + 1) * 64), q1b = *(const v2f*)(wp + (i + 1) * 64 + 2);
        v2f q2a = *(const v2f*)(wp + (i + 2) * 64), q2b = *(const v2f*)(wp + (i + 2) * 64 + 2);
        v2f q3a = *(const v2f*)(wp + (i + 3) * 64), q3b = *(const v2f*)(wp + (i + 3) * 64 + 2);
        v2f s;
        s = (v2f){a0.x, a0.x}; acc0a = v2fma(s, q0a, acc0a); acc0b = v2fma(s, q0b, acc0b);
        s = (v2f){a0.y, a0.y}; acc0a = v2fma(s, q1a, acc0a); acc0b = v2fma(s, q1b, acc0b);
        s = (v2f){a0.z, a0.z}; acc0a = v2fma(s, q2a, acc0a); acc0b = v2fma(s, q2b, acc0b);
        s = (v2f){a0.w, a0.w}; acc0a = v2fma(s, q3a, acc0a); acc0b = v2fma(s, q3b, acc0b);
        s = (v2f){a1.x, a1.x}; acc1a = v2fma(s, q0a, acc1a); acc1b = v2fma(s, q0b, acc1b);
        s = (v2f){a1.y, a1.y}; acc1a = v2fma(s, q1a, acc1a); acc1b = v2fma(s, q1b, acc1b);
        s = (v2f){a1.z, a1.z}; acc1a = v2fma(s, q2a, acc1a); acc1b = v2fma(s, q2b, acc1b);
        s = (v2f){a1.w, a1.w}; acc1a = v2fma(s, q3a, acc1a); acc1b = v2fma(s, q3b, acc1b);
    }
    o0[0] = acc0a.x; o0[1] = acc0a.y; o0[2] = acc0b.x; o0[3] = acc0b.y;
    o1[0] = acc1a.x; o1[1] = acc1a.y; o1[2] = acc1b.x; o1[3] = acc1b.y;
}

// ---- R24 merged dual-weight core (k_epi W0+W1, both from LDS): reads
// each A float4 ONCE, feeds both accumulator sets. Per-output k-order
// identical to two gemm_core_pk calls -> bit-identical results. ----
__device__ __forceinline__ void gemm2_core_pk(const float (*in)[68],
                                              const float* w0, const float* w1,
                                              const float* c0, const float* c1,
                                              int rg, int cg,
                                              float (&x0)[4], float (&x1)[4],
                                              float (&y0)[4], float (&y1)[4])
{
    v2f A0a = {c0[4*cg], c0[4*cg+1]}, A0b = {c0[4*cg+2], c0[4*cg+3]};
    v2f A1a = A0a, A1b = A0b;
    v2f B0a = {c1[4*cg], c1[4*cg+1]}, B0b = {c1[4*cg+2], c1[4*cg+3]};
    v2f B1a = B0a, B1b = B0b;
    const int r0 = 2 * rg, r1 = 2 * rg + 1;
#pragma unroll
    for (int i = 0; i < 64; i += 4) {
        float4 a0 = *(const float4*)&in[r0][i];
        float4 a1 = *(const float4*)&in[r1][i];
        const float* q = &w0[i * 64 + 4 * cg];
        const float* p = &w1[i * 64 + 4 * cg];
        v2f q0a = *(const v2f*)(q),       q0b = *(const v2f*)(q + 2);
        v2f q1a = *(const v2f*)(q + 64),  q1b = *(const v2f*)(q + 66);
        v2f q2a = *(const v2f*)(q + 128), q2b = *(const v2f*)(q + 130);
        v2f q3a = *(const v2f*)(q + 192), q3b = *(const v2f*)(q + 194);
        v2f s;
        s = (v2f){a0.x, a0.x}; A0a = v2fma(s, q0a, A0a); A0b = v2fma(s, q0b, A0b);
        s = (v2f){a0.y, a0.y}; A0a = v2fma(s, q1a, A0a); A0b = v2fma(s, q1b, A0b);
        s = (v2f){a0.z, a0.z}; A0a = v2fma(s, q2a, A0a); A0b = v2fma(s, q2b, A0b);
        s = (v2f){a0.w, a0.w}; A0a = v2fma(s, q3a, A0a); A0b = v2fma(s, q3b, A0b);
        s = (v2f){a1.x, a1.x}; A1a = v2fma(s, q0a, A1a); A1b = v2fma(s, q0b, A1b);
        s = (v2f){a1.y, a1.y}; A1a = v2fma(s, q1a, A1a); A1b = v2fma(s, q1b, A1b);
        s = (v2f){a1.z, a1.z}; A1a = v2fma(s, q2a, A1a); A1b = v2fma(s, q2b, A1b);
        s = (v2f){a1.w, a1.w}; A1a = v2fma(s, q3a, A1a); A1b = v2fma(s, q3b, A1b);
        v2f p0a = *(const v2f*)(p),       p0b = *(const v2f*)(p + 2);
        v2f p1a = *(const v2f*)(p + 64),  p1b = *(const v2f*)(p + 66);
        v2f p2a = *(const v2f*)(p + 128), p2b = *(const v2f*)(p + 130);
        v2f p3a = *(const v2f*)(p + 192), p3b = *(const v2f*)(p + 194);
        s = (v2f){a0.x, a0.x}; B0a = v2fma(s, p0a, B0a); B0b = v2fma(s, p0b, B0b);
        s = (v2f){a0.y, a0.y}; B0a = v2fma(s, p1a, B0a); B0b = v2fma(s, p1b, B0b);
        s = (v2f){a0.z, a0.z}; B0a = v2fma(s, p2a, B0a); B0b = v2fma(s, p2b, B0b);
        s = (v2f){a0.w, a0.w}; B0a = v2fma(s, p3a, B0a); B0b = v2fma(s, p3b, B0b);
        s = (v2f){a1.x, a1.x}; B1a = v2fma(s, p0a, B1a); B1b = v2fma(s, p0b, B1b);
        s = (v2f){a1.y, a1.y}; B1a = v2fma(s, p1a, B1a); B1b = v2fma(s, p1b, B1b);
        s = (v2f){a1.z, a1.z}; B1a = v2fma(s, p2a, B1a); B1b = v2fma(s, p2b, B1b);
        s = (v2f){a1.w, a1.w}; B1a = v2fma(s, p3a, B1a); B1b = v2fma(s, p3b, B1b);
    }
    x0[0] = A0a.x; x0[1] = A0a.y; x0[2] = A0b.x; x0[3] = A0b.y;
    x1[0] = A1a.x; x1[1] = A1a.y; x1[2] = A1b.x; x1[3] = A1b.y;
    y0[0] = B0a.x; y0[1] = B0a.y; y0[2] = B0b.x; y0[3] = B0b.y;
    y1[0] = B1a.x; y1[1] = B1a.y; y1[2] = B1b.x; y1[3] = B1b.y;
}

// ---- R20 packed R17 core: per-wave tile, 4 rows x 4 cols/thread, weights
// from global/L1; unroll 2 bounds in-flight loads (full unroll = spill). ----
__device__ __forceinline__ void gemm4_pk(const float (*in)[68], const float* __restrict__ w,
                                         const float* b, int rgs, int cg,
                                         float (&out)[4][4])
{
    float bb0 = b[4*cg], bb1 = b[4*cg+1], bb2 = b[4*cg+2], bb3 = b[4*cg+3];
    v2f ba = {bb0, bb1}, bbv = {bb2, bb3};
    v2f acc[4][2];
#pragma unroll
    for (int r = 0; r < 4; r++) { acc[r][0] = ba; acc[r][1] = bbv; }
    const float* wp = w + 4 * cg;
    const int r0 = 4 * rgs;
#pragma unroll 2
    for (int i = 0; i < 64; i += 4) {
        v2f q0a = *(const v2f*)(wp + (i + 0) * 64), q0b = *(const v2f*)(wp + (i + 0) * 64 + 2);
        v2f q1a = *(const v2f*)(wp + (i + 1) * 64), q1b = *(const v2f*)(wp + (i + 1) * 64 + 2);
        v2f q2a = *(const v2f*)(wp + (i + 2) * 64), q2b = *(const v2f*)(wp + (i + 2) * 64 + 2);
        v2f q3a = *(const v2f*)(wp + (i + 3) * 64), q3b = *(const v2f*)(wp + (i + 3) * 64 + 2);
#pragma unroll
        for (int r = 0; r < 4; r++) {
            float4 a = *(const float4*)&in[r0 + r][i];
            v2f s;
            s = (v2f){a.x, a.x}; acc[r][0] = v2fma(s, q0a, acc[r][0]); acc[r][1] = v2fma(s, q0b, acc[r][1]);
            s = (v2f){a.y, a.y}; acc[r][0] = v2fma(s, q1a, acc[r][0]); acc[r][1] = v2fma(s, q1b, acc[r][1]);
            s = (v2f){a.z, a.z}; acc[r][0] = v2fma(s, q2a, acc[r][0]); acc[r][1] = v2fma(s, q2b, acc[r][1]);
            s = (v2f){a.w, a.w}; acc[r][0] = v2fma(s, q3a, acc[r][0]); acc[r][1] = v2fma(s, q3b, acc[r][1]);
        }
    }
#pragma unroll
    for (int r = 0; r < 4; r++) {
        out[r][0] = acc[r][0].x; out[r][1] = acc[r][0].y;
        out[r][2] = acc[r][1].x; out[r][3] = acc[r][1].y;
    }
}

// ---------------- CSR build: LDS-staged bucket sort (R13/R22/R23) ----------------

__global__ __launch_bounds__(256) void k_bhist(const int* __restrict__ col,
                                               int* __restrict__ bhist, int e)
{
    __shared__ int hist[256];
    int t = threadIdx.x;
    hist[t] = 0;
    __syncthreads();
    int base = blockIdx.x * SCT;
    int end = min(e, base + SCT);
    for (int i = base + t; i < end; i += 256)
        atomicAdd(&hist[col[i] >> 9], 1);
    __syncthreads();
    if (hist[t]) atomicAdd(&bhist[t], hist[t]);
}

__global__ __launch_bounds__(256) void k_bscan(const int* __restrict__ bhist,
                                               int* __restrict__ bbase, int* __restrict__ bcur)
{
    __shared__ int s[256];
    int t = threadIdx.x;
    int v = bhist[t];
    s[t] = v;
    __syncthreads();
    for (int d = 1; d < 256; d <<= 1) {
        int u = (t >= d) ? s[t - d] : 0;
        __syncthreads();
        s[t] += u;
        __syncthreads();
    }
    int b = s[t] - v;
    bbase[t] = b;
    bcur[t] = b;
}

// R23: pairs packed as u32: row in [0,17), (col&511) in [17,26).
__global__ __launch_bounds__(256) void k_bscatter2(const int* __restrict__ row,
    const int* __restrict__ col, int* __restrict__ bcur,
    unsigned* __restrict__ pairs, int e, int nbk)
{
    __shared__ int hist[256], lcur[256], gb[256], s[256];
    __shared__ unsigned buf[SCT];
    int t = threadIdx.x;
    int base = blockIdx.x * SCT;
    int end = min(e, base + SCT);
    hist[t] = 0;
    __syncthreads();
    for (int i = base + t; i < end; i += 256)
        atomicAdd(&hist[col[i] >> 9], 1);
    __syncthreads();
    int v = hist[t];
    s[t] = v;
    __syncthreads();
    for (int d = 1; d < 256; d <<= 1) {
        int u = (t >= d) ? s[t - d] : 0;
        __syncthreads();
        s[t] += u;
        __syncthreads();
    }
    lcur[t] = s[t] - v;
    __syncthreads();
    for (int i = base + t; i < end; i += 256) {
        int c = col[i];
        int slot = atomicAdd(&lcur[c >> 9], 1);
        buf[slot] = (unsigned)row[i] | ((unsigned)(c & 511) << 17);
    }
    if (v > 0) gb[t] = atomicAdd(&bcur[t], v);
    __syncthreads();
    // R22: stripe buckets across the 4 waves (disjoint buckets, read-only
    // metadata after the barrier).
    int wv = t >> 6, lane = t & 63;
    for (int b = wv; b < nbk; b += 4) {
        int cnt = hist[b];
        if (cnt == 0) continue;
        int lo = s[b] - cnt;
        int go = gb[b];
        for (int j = lane; j < cnt; j += 64)
            pairs[go + j] = buf[lo + j];
    }
}

__global__ __launch_bounds__(256) void k_fill3(const unsigned* __restrict__ pairs,
    const int* __restrict__ bbase, const int* __restrict__ bhist,
    int* __restrict__ arr, int* __restrict__ csr, int n)
{
    __shared__ int nh[512], nc[512], s[256];
    __shared__ unsigned sbuf[F3CAP];      // R23: stage packed pairs once
    int b = blockIdx.x, t = threadIdx.x;
    int pbase = bbase[b];
    int cnt = bhist[b];
    int nodebase = b << 9;
    nh[t] = 0; nh[t + 256] = 0;
    __syncthreads();
    for (int i = t; i < cnt; i += 256) {
        unsigned pv = pairs[pbase + i];
        if (i < F3CAP) sbuf[i] = pv;
        atomicAdd(&nh[pv >> 17], 1);
    }
    __syncthreads();
    int v0 = nh[2 * t], v1 = nh[2 * t + 1];
    int sum = v0 + v1;
    s[t] = sum;
    __syncthreads();
    for (int d = 1; d < 256; d <<= 1) {
        int u = (t >= d) ? s[t - d] : 0;
        __syncthreads();
        s[t] += u;
        __syncthreads();
    }
    int excl = s[t] - sum;
    int n0 = nodebase + 2 * t, n1 = n0 + 1;
    nc[2 * t]     = pbase + excl;
    nc[2 * t + 1] = pbase + excl + v0;
    if (n0 < n) arr[n0] = pbase + excl + v0;
    if (n1 < n) arr[n1] = pbase + excl + v0 + v1;
    __syncthreads();
    for (int i = t; i < cnt; i += 256) {
        unsigned pv = (i < F3CAP) ? sbuf[i] : pairs[pbase + i];
        int p = atomicAdd(&nc[pv >> 17], 1);
        csr[p] = (int)(pv & 0x1FFFFu);
    }
}

// ---------------- weight precombination ----------------
// pre layout (floats): W0[4096] | W1[4096] | c0[64]@8192 | c1[64]@8256 |
//                      u0[128]@8320 | u1[128]@8448 | v[4]@8576

__global__ __launch_bounds__(256) void k_pre(
    const float* __restrict__ wg1, const float* __restrict__ bg1,
    const float* __restrict__ wg2, const float* __restrict__ bg2,
    const float* __restrict__ wf,  const float* __restrict__ bf,
    const float* __restrict__ wc,  float* __restrict__ pre)
{
    __shared__ float wfs[4096];
    __shared__ float wcs[128];
    int t = threadIdx.x;
    for (int i = t; i < 4096; i += 256) wfs[i] = wf[i];
    if (t < 128) wcs[t] = wc[t];
    __syncthreads();
    int i = t & 63, jb = (t >> 6) * 16;
    float acc0[16], acc1[16];
#pragma unroll
    for (int j = 0; j < 16; j++) { acc0[j] = 0.f; acc1[j] = 0.f; }
#pragma unroll 1
    for (int k = 0; k < 64; k++) {
        float a = wg1[i * 64 + k];
        float b = wg2[i * 64 + k];
#pragma unroll
        for (int j = 0; j < 16; j++) {
            float w = wfs[k * 64 + jb + j];
            acc0[j] = fmaf(a, w, acc0[j]);
            acc1[j] = fmaf(b, w, acc1[j]);
        }
    }
#pragma unroll
    for (int j = 0; j < 16; j++) {
        pre[i * 64 + jb + j]        = acc0[j];
        pre[4096 + i * 64 + jb + j] = acc1[j];
    }
    if (t < 64) {
        float s0 = bf[t], s1 = bf[t];
#pragma unroll 1
        for (int m = 0; m < 64; m++) {
            s0 = fmaf(bg1[m], wfs[m * 64 + t], s0);
            s1 = fmaf(bg2[m], wfs[m * 64 + t], s1);
        }
        pre[8192 + t] = s0;
        pre[8256 + t] = s1;
        float u00 = 0.f, u01 = 0.f, u10 = 0.f, u11 = 0.f;
#pragma unroll 1
        for (int m = 0; m < 64; m++) {
            float g1 = wg1[t * 64 + m], g2 = wg2[t * 64 + m];
            u00 = fmaf(g1, wcs[m * 2 + 0], u00);
            u01 = fmaf(g1, wcs[m * 2 + 1], u01);
            u10 = fmaf(g2, wcs[m * 2 + 0], u10);
            u11 = fmaf(g2, wcs[m * 2 + 1], u11);
        }
        pre[8320 + t * 2]     = u00;
        pre[8320 + t * 2 + 1] = u01;
        pre[8448 + t * 2]     = u10;
        pre[8448 + t * 2 + 1] = u11;
    }
    if (t == 0) {
        float v00 = 0.f, v01 = 0.f, v10 = 0.f, v11 = 0.f;
#pragma unroll 1
        for (int m = 0; m < 64; m++) {
            v00 = fmaf(bg1[m], wcs[m * 2 + 0], v00);
            v01 = fmaf(bg1[m], wcs[m * 2 + 1], v01);
            v10 = fmaf(bg2[m], wcs[m * 2 + 0], v10);
            v11 = fmaf(bg2[m], wcs[m * 2 + 1], v11);
        }
        pre[8576] = v00; pre[8577] = v01; pre[8578] = v10; pre[8579] = v11;
    }
}

// ---------------- node MLP: per-wave 16-row tile, barrier-free (R17, packed R20) ----------------

__global__ __launch_bounds__(256) void k_mlp(const float* __restrict__ x,
    const float* __restrict__ w1, const float* __restrict__ b1,
    const float* __restrict__ w2, const float* __restrict__ b2,
    const float* __restrict__ w3, const float* __restrict__ b3,
    const int* __restrict__ arr, float* __restrict__ h,
    float2* __restrict__ nrm2, int n)
{
    __shared__ float b1s[64], b2s[64], b3s[64];
    __shared__ float xs[4][16][68];          // one 16-row slice per wave
    int t = threadIdx.x;
    if (t < 64) { b1s[t] = b1[t]; b2s[t] = b2[t]; b3s[t] = b3[t]; }
    __syncthreads();                          // once, for biases only
    int wv = t >> 6, lane = t & 63;
    int cg = lane & 15, rgs = lane >> 4;      // thread: rows 4*rgs..+3, cols 4*cg..+3
    int row0 = blockIdx.x * 64 + wv * 16;     // this wave's 16 rows
    float (*ws)[68] = xs[wv];

    // stage: lane stages row lane>>2, cols (lane&3)*16 (wave reads 4KB contiguous)
    {
        int r = lane >> 2, c = (lane & 3) * 16;
        int grow = row0 + r;
        float4 v0 = make_float4(0.f,0.f,0.f,0.f), v1 = v0, v2 = v0, v3 = v0;
        if (grow < n) {
            const float* p = x + (size_t)grow * 64 + c;
            v0 = *(const float4*)p;       v1 = *(const float4*)(p + 4);
            v2 = *(const float4*)(p + 8); v3 = *(const float4*)(p + 12);
        }
        *(float4*)&ws[r][c]      = v0; *(float4*)&ws[r][c + 4]  = v1;
        *(float4*)&ws[r][c + 8]  = v2; *(float4*)&ws[r][c + 12] = v3;
    }
    lds_fence();

    float acc[4][4];
    // layer 1: read xs slice, relu, overwrite in place (lockstep: all wave
    // reads precede the write instructions; fences order DS completion)
    gemm4_pk(ws, w1, b1s, rgs, cg, acc);
    lds_fence();
#pragma unroll
    for (int r = 0; r < 4; r++)
        *(float4*)&ws[4 * rgs + r][4 * cg] =
            make_float4(fmaxf(acc[r][0], 0.f), fmaxf(acc[r][1], 0.f),
                        fmaxf(acc[r][2], 0.f), fmaxf(acc[r][3], 0.f));
    lds_fence();
    // layer 2
    gemm4_pk(ws, w2, b2s, rgs, cg, acc);
    lds_fence();
#pragma unroll
    for (int r = 0; r < 4; r++)
        *(float4*)&ws[4 * rgs + r][4 * cg] =
            make_float4(fmaxf(acc[r][0], 0.f), fmaxf(acc[r][1], 0.f),
                        fmaxf(acc[r][2], 0.f), fmaxf(acc[r][3], 0.f));
    lds_fence();
    // layer 3 + fused per-node scalars
    gemm4_pk(ws, w3, b3s, rgs, cg, acc);

    int r0g = row0 + 4 * rgs;
    float sr[4];
#pragma unroll
    for (int r = 0; r < 4; r++) {
        int grow = r0g + r;
        if (grow < n)
            *(float4*)&h[(size_t)grow * 64 + 4 * cg] =
                make_float4(acc[r][0], acc[r][1], acc[r][2], acc[r][3]);
        sr[r] = acc[r][0]*acc[r][0] + acc[r][1]*acc[r][1]
              + acc[r][2]*acc[r][2] + acc[r][3]*acc[r][3];
    }
#pragma unroll
    for (int d = 1; d < 16; d <<= 1) {
#pragma unroll
        for (int r = 0; r < 4; r++) sr[r] += __shfl_xor(sr[r], d, 64);
    }
    if (cg == 0) {
#pragma unroll
        for (int r = 0; r < 4; r++) {
            int grow = r0g + r;
            if (grow < n) {
                int st = (grow == 0) ? 0 : arr[grow - 1];
                nrm2[grow] = make_float2(1.0f / (sqrtf(sr[r]) + 1e-12f),
                                         rsqrtf((float)(arr[grow] - st + 1)));
            }
        }
    }
}

// ---------------- edge pass: 2 nodes/wave, per half 4 edge-groups x 8 lanes (R18/R20) ----------------

__global__ __launch_bounds__(256) void k_gather(const float* __restrict__ h,
    const int* __restrict__ arr, const int* __restrict__ csr,
    const float2* __restrict__ nrm2, const float* __restrict__ beta_p,
    const float* __restrict__ wc,
    float* __restrict__ agg, float2* __restrict__ yp, int n)
{
    // [wave][g][sub][col+pad]: pad 66 -> write banks (4g+2sub+8s)%32 cover
    // all 32 banks at 8 words/bank (floor). 16.9KB total.
    __shared__ float reda[4][4][2][66];
    __shared__ float redn[4][4][2][66];
    int wv = threadIdx.x >> 6;
    int lane = threadIdx.x & 63;
    int sub = lane >> 5;              // which node in this wave
    int l32 = lane & 31;              // lane within half
    int g = l32 >> 3, s = l32 & 7;    // 4 groups x 8 lanes per half
    int base = sub << 5;              // absolute lane offset of this half
    int node = blockIdx.x * 8 + wv * 2 + sub;
    bool valid = node < n;
    int nd = valid ? node : 0;
    float beta = beta_p[0];
    const char* hb = (const char*)h;

    // self row: lane covers cols 8s..8s+7 (32-bit byte offset -> SADDR loads)
    unsigned selfoff = ((unsigned)nd << 8) + ((unsigned)s << 5);
    float4 hA = *(const float4*)(hb + selfoff);
    float4 hB = *(const float4*)(hb + selfoff + 16);
    v2f hc0 = {hA.x, hA.y}, hc1 = {hA.z, hA.w};
    v2f hc2 = {hB.x, hB.y}, hc3 = {hB.z, hB.w};

    v2f sv = hc0 * hc0;
    sv = v2fma(hc1, hc1, sv); sv = v2fma(hc2, hc2, sv); sv = v2fma(hc3, hc3, sv);
    float ss = sv.x + sv.y;
#pragma unroll
    for (int d = 1; d < 8; d <<= 1) ss += __shfl_xor(ss, d, 64);   // within group
    float2 ncv = nrm2[nd];
    float rnc = ncv.x, dc = ncv.y;
    float brn = beta * rnc;                 // hoisted: w = exp(brn * p * rnr)
    float wself = __expf(brn * ss * rnc);

    v2f a0 = {0.f,0.f}, a1 = {0.f,0.f}, a2 = {0.f,0.f}, a3 = {0.f,0.f};
    v2f n0 = {0.f,0.f}, n1 = {0.f,0.f}, n2 = {0.f,0.f}, n3 = {0.f,0.f};
    float denom = 0.f;
    if (g == 0) {                           // self-loop contribution, once per half
        v2f dcv = {dc, dc}, wsv = {wself, wself};
        a0 = dcv * hc0; a1 = dcv * hc1; a2 = dcv * hc2; a3 = dcv * hc3;
        n0 = wsv * hc0; n1 = wsv * hc1; n2 = wsv * hc2; n3 = wsv * hc3;
        denom = wself;
    }

    int start = (!valid || nd == 0) ? 0 : arr[nd - 1];
    int end = valid ? arr[nd] : 0;
#pragma unroll 1
    for (int k0 = start; k0 < end; k0 += 32) {
        int m = min(32, end - k0);
        int idx = 0; float rv = 0.f, dv = 0.f;
        if (l32 < m) {
            idx = csr[k0 + l32];
            float2 ndv = nrm2[idx];
            rv = ndv.x; dv = ndv.y;
        }
        int ei = __shfl(idx, base + g, 64);
        unsigned eoff = ((unsigned)ei << 8) + ((unsigned)s << 5);
        float4 cA = *(const float4*)(hb + eoff);
        float4 cB = *(const float4*)(hb + eoff + 16);
#pragma unroll 1
        for (int k = 0; k < m; k += 4) {
            float4 fA = cA, fB = cB;
            if (k + 4 < m) {
                int e2 = __shfl(idx, base + k + 4 + g, 64);
                unsigned off2 = ((unsigned)e2 << 8) + ((unsigned)s << 5);
                cA = *(const float4*)(hb + off2);
                cB = *(const float4*)(hb + off2 + 16);
            }
            float rnr = __shfl(rv, base + k + g, 64);
            float dvr = __shfl(dv, base + k + g, 64);
            v2f f0 = {fA.x, fA.y}, f1 = {fA.z, fA.w};
            v2f f2 = {fB.x, fB.y}, f3 = {fB.z, fB.w};
            // dot(h[src], h[dst]) over this lane's 8 cols, packed
            v2f ps = f0 * hc0;
            ps = v2fma(f1, hc1, ps); ps = v2fma(f2, hc2, ps); ps = v2fma(f3, hc3, ps);
            float p = ps.x + ps.y;
#pragma unroll
            for (int d = 1; d < 8; d <<= 1) p += __shfl_xor(p, d, 64);
            bool act = (k + g) < m;
            float w   = act ? __expf(brn * p * rnr) : 0.f;
            float dve = act ? dvr : 0.f;
            v2f wsp = {w, w}, dsp = {dve, dve};
            a0 = v2fma(dsp, f0, a0); a1 = v2fma(dsp, f1, a1);
            a2 = v2fma(dsp, f2, a2); a3 = v2fma(dsp, f3, a3);
            n0 = v2fma(wsp, f0, n0); n1 = v2fma(wsp, f1, n1);
            n2 = v2fma(wsp, f2, n2); n3 = v2fma(wsp, f3, n3);
            denom += w;
        }
    }

    // ---- cross-group reduce via padded LDS transpose ----
    {
        float* wa = &reda[wv][g][sub][8 * s];
        float* wn = &redn[wv][g][sub][8 * s];
        *(float4*)wa       = make_float4(a0.x, a0.y, a1.x, a1.y);
        *(float4*)(wa + 4) = make_float4(a2.x, a2.y, a3.x, a3.y);
        *(float4*)wn       = make_float4(n0.x, n0.y, n1.x, n1.y);
        *(float4*)(wn + 4) = make_float4(n2.x, n2.y, n3.x, n3.y);
    }
    lds_fence();
    // lane (sub,l32) sums cols l32 and l32+32 of its node across the 4 groups
    float a_lo, a_hi, n_lo, n_hi;
    {
        const float* r0p = &reda[wv][0][sub][0];
        const float* r1p = &redn[wv][0][sub][0];
        float t0 = r0p[l32]       + r0p[132 + l32];
        float t1 = r0p[264 + l32] + r0p[396 + l32];
        float t2 = r0p[l32 + 32]       + r0p[132 + l32 + 32];
        float t3 = r0p[264 + l32 + 32] + r0p[396 + l32 + 32];
        a_lo = t0 + t1; a_hi = t2 + t3;
        float u0 = r1p[l32]       + r1p[132 + l32];
        float u1 = r1p[264 + l32] + r1p[396 + l32];
        float u2 = r1p[l32 + 32]       + r1p[132 + l32 + 32];
        float u3 = r1p[264 + l32 + 32] + r1p[396 + l32 + 32];
        n_lo = u0 + u1; n_hi = u2 + u3;
    }
    if (valid) {
        agg[(size_t)node * 64 + l32]      = dc * a_lo;
        agg[(size_t)node * 64 + l32 + 32] = dc * a_hi;
    }

    // denom varies only across g within the half: 2-stage reduce
    denom += __shfl_xor(denom, 8, 64);
    denom += __shfl_xor(denom, 16, 64);

    // classifier contribution of h1: lane owns cols l32 and l32+32
    float2 w_lo = *(const float2*)(wc + 128 + 2 * l32);
    float2 w_hi = *(const float2*)(wc + 128 + 2 * (l32 + 32));
    float cx = n_lo * w_lo.x + n_hi * w_hi.x;
    float cy = n_lo * w_lo.y + n_hi * w_hi.y;
#pragma unroll
    for (int d = 1; d < 32; d <<= 1) { cx += __shfl_xor(cx, d, 64); cy += __shfl_xor(cy, d, 64); }
    if (l32 == 0 && valid) {
        float inv = 1.0f / denom;
        yp[node] = make_float2(cx * inv, cy * inv);
    }
}

// ---------------- epilogue: W0/W1 in LDS (merged), wx streamed (R24) ----------------

__global__ __launch_bounds__(256) void k_epi(const float* __restrict__ agg,
    const float* __restrict__ hbuf, const float2* __restrict__ yp,
    const float* __restrict__ pre, const float* __restrict__ wx,
    const float* __restrict__ bx, const float* __restrict__ bc,
    float* __restrict__ y, int n, int ntiles)
{
    __shared__ float W0s[4096], W1s[4096];
    __shared__ float c0s[64], c1s[64], bxs[64], us[256], vs[4], bcs[2];
    __shared__ float A[32][68], H[32][68];
    int t = threadIdx.x;
    for (int i = t; i < 4096; i += 256) { W0s[i] = pre[i]; W1s[i] = pre[4096 + i]; }
    if (t < 64) { c0s[t] = pre[8192 + t]; c1s[t] = pre[8256 + t]; bxs[t] = bx[t]; }
    us[t] = pre[8320 + t];
    if (t < 4) vs[t] = pre[8576 + t];
    if (t < 2) bcs[t] = bc[t];
    __syncthreads();
    int cg = t & 15, rg = t >> 4;
    for (int tile = blockIdx.x; tile < ntiles; tile += gridDim.x) {
        int row0 = tile * 32;
        load_rows32(agg,  row0, n, A, t);
        load_rows32(hbuf, row0, n, H, t);
        __syncthreads();
        int r0g = row0 + 2 * rg, r1g = r0g + 1;
        float xp0[4], xp1[4];
        gemm_gw_pk(H, wx, bxs, rg, cg, xp0, xp1);       // R24: wx streamed from L1
#pragma unroll
        for (int j = 0; j < 4; j++) { xp0[j] = fast_tanh(xp0[j]); xp1[j] = fast_tanh(xp1[j]); }
        float a0[4], a1[4], b0[4], b1[4];
        gemm2_core_pk(A, W0s, W1s, c0s, c1s, rg, cg, a0, a1, b0, b1);  // R24: merged
        float l00 = 0.f, l01 = 0.f, l10 = 0.f, l11 = 0.f;
#pragma unroll
        for (int j = 0; j < 4; j++) {
            l00 = fmaf(fast_tanh(a0[j]), xp0[j], l00);
            l01 = fmaf(fast_tanh(a1[j]), xp1[j], l01);
            l10 = fmaf(fast_tanh(b0[j]), xp0[j], l10);
            l11 = fmaf(fast_tanh(b1[j]), xp1[j], l11);
        }
        float4 av0 = *(const float4*)&A[2 * rg][4 * cg];
        float4 av1 = *(const float4*)&A[2 * rg + 1][4 * cg];
        float za0=0.f, za1=0.f, zb0=0.f, zb1=0.f;
        float zc0=0.f, zc1=0.f, zd0=0.f, zd1=0.f;
#pragma unroll
        for (int j = 0; j < 4; j++) {
            int k = 4 * cg + j;
            float u0c0 = us[k * 2], u0c1 = us[k * 2 + 1];
            float u1c0 = us[128 + k * 2], u1c1 = us[128 + k * 2 + 1];
            float p0 = (&av0.x)[j], p1 = (&av1.x)[j];
            za0 = fmaf(p0, u0c0, za0); za1 = fmaf(p0, u0c1, za1);
            zb0 = fmaf(p0, u1c0, zb0); zb1 = fmaf(p0, u1c1, zb1);
            zc0 = fmaf(p1, u0c0, zc0); zc1 = fmaf(p1, u0c1, zc1);
            zd0 = fmaf(p1, u1c0, zd0); zd1 = fmaf(p1, u1c1, zd1);
        }
#pragma unroll
        for (int d = 1; d < 16; d <<= 1) {
            l00 += __shfl_xor(l00, d, 64); l01 += __shfl_xor(l01, d, 64);
            l10 += __shfl_xor(l10, d, 64); l11 += __shfl_xor(l11, d, 64);
            za0 += __shfl_xor(za0, d, 64); za1 += __shfl_xor(za1, d, 64);
            zb0 += __shfl_xor(zb0, d, 64); zb1 += __shfl_xor(zb1, d, 64);
            zc0 += __shfl_xor(zc0, d, 64); zc1 += __shfl_xor(zc1, d, 64);
            zd0 += __shfl_xor(zd0, d, 64); zd1 += __shfl_xor(zd1, d, 64);
        }
        if (cg == 0) {
            if (r0g < n) {
                float mx = fmaxf(l00, l10);
                float e0 = __expf(l00 - mx), e1 = __expf(l10 - mx);
                float inv = 1.0f / (e0 + e1);
                float s0 = e0 * inv, s1 = e1 * inv;
                float2 ypv = yp[r0g];
                float y0v = s0 * (za0 + vs[0]) + s1 * (zb0 + vs[2]) + ypv.x + bcs[0];
                float y1v = s0 * (za1 + vs[1]) + s1 * (zb1 + vs[3]) + ypv.y + bcs[1];
                *(float2*)&y[(size_t)r0g * 2] = make_float2(y0v, y1v);
            }
            if (r1g < n) {
                float mx = fmaxf(l01, l11);
                float e0 = __expf(l01 - mx), e1 = __expf(l11 - mx);
                float inv = 1.0f / (e0 + e1);
                float s0 = e0 * inv, s1 = e1 * inv;
                float2 ypv = yp[r1g];
                float y0v = s0 * (zc0 + vs[0]) + s1 * (zd0 + vs[2]) + ypv.x + bcs[0];
                float y1v = s0 * (zc1 + vs[1]) + s1 * (zd1 + vs[3]) + ypv.y + bcs[1];
                *(float2*)&y[(size_t)r1g * 2] = make_float2(y0v, y1v);
            }
        }
        __syncthreads();
    }
}

extern "C" void kernel_launch(void* const* d_in, const int* in_sizes, int n_in,
                              void* d_out, int out_size, void* d_ws, size_t ws_size,
                              hipStream_t stream)
{
    const float* x    = (const float*)d_in[0];
    const int*   ei   = (const int*)d_in[1];
    const float* w1   = (const float*)d_in[2];
    const float* b1   = (const float*)d_in[3];
    const float* w2   = (const float*)d_in[4];
    const float* b2   = (const float*)d_in[5];
    const float* w3   = (const float*)d_in[6];
    const float* b3   = (const float*)d_in[7];
    const float* wg1  = (const float*)d_in[8];
    const float* bg1  = (const float*)d_in[9];
    const float* wg2  = (const float*)d_in[10];
    const float* bg2  = (const float*)d_in[11];
    const float* beta = (const float*)d_in[12];
    const float* wf   = (const float*)d_in[13];
    const float* bf   = (const float*)d_in[14];
    const float* wx   = (const float*)d_in[15];
    const float* bx   = (const float*)d_in[16];
    const float* wc   = (const float*)d_in[17];
    const float* bc   = (const float*)d_in[18];
    float* y = (float*)d_out;

    int n = in_sizes[0] / 64;     // 100000
    int e = in_sizes[1] / 2;      // 1600000
    const int* row = ei;
    const int* col = ei + e;

    // workspace ~34MB
    char* p = (char*)d_ws;
    auto alloc = [&](size_t bytes) { char* q = p; p += (bytes + 255) & ~(size_t)255; return q; };
    float*  h    = (float*)alloc((size_t)n * 64 * 4);    // 25.6MB (pairs -> h)
    int*    csr  = (int*)alloc((size_t)e * 4);           // 6.4MB
    float2* nrm2 = (float2*)alloc((size_t)n * 8);        // 0.8MB
    int*    arr  = (int*)alloc((size_t)(n + 1) * 4);     // 0.4MB
    float2* yp   = (float2*)alloc((size_t)n * 8);        // 0.8MB
    float*  pre  = (float*)alloc(8704 * 4);              // combined weights
    int*    bhist = (int*)alloc(256 * 4);
    int*    bbase = (int*)alloc(256 * 4);
    int*    bcur  = (int*)alloc(256 * 4);

    // packed pairs buffer (6.4MB) aliases h: consumed by k_fill3 before
    // k_mlp writes h.
    unsigned* pairs = (unsigned*)h;
    // agg reuses x's buffer (x dead after k_mlp; harness restores d_in).
    float* agg = (float*)d_in[0];

    int ntiles = (n + 31) / 32;            // 3125 32-row tiles (k_epi)
    int ntile64 = (n + 63) / 64;           // 1563 64-row tiles (k_mlp)
    int nbk = (n + 511) >> 9;              // 196 buckets (col>>9)
    int nsct = (e + SCT - 1) / SCT;        // 256 scatter tiles (R23)

    k_pre<<<1, 256, 0, stream>>>(wg1, bg1, wg2, bg2, wf, bf, wc, pre);
    hipMemsetAsync(bhist, 0, 256 * sizeof(int), stream);
    k_bhist<<<nsct, 256, 0, stream>>>(col, bhist, e);
    k_bscan<<<1, 256, 0, stream>>>(bhist, bbase, bcur);
    k_bscatter2<<<nsct, 256, 0, stream>>>(row, col, bcur, pairs, e, nbk);
    k_fill3<<<nbk, 256, 0, stream>>>(pairs, bbase, bhist, arr, csr, n);
    k_mlp<<<ntile64, 256, 0, stream>>>(x, w1, b1, w2, b2, w3, b3, arr, h, nrm2, n);
    k_gather<<<(n + 7) / 8, 256, 0, stream>>>(h, arr, csr, nrm2, beta, wc, agg, yp, n);
    k_epi<<<1024, 256, 0, stream>>>(agg, h, yp, pre, wx, bx, bc, y, n, ntiles);
}

// Round 10
// 373.634 us; speedup vs baseline: 1.0157x; 1.0157x over previous
//
#include <hip/hip_runtime.h>
#include <math.h>

// N=100000 nodes, E=1600000 edges, HID=64, C=2, fp32.
// Hard-won constraints (R2-R24):
//  * FULLY-unrolled global-weight loads -> VGPR hoist -> spill (R2/R3);
//    #pragma unroll 2 bounds in-flight loads.
//  * 512-thread blocks unusable (VGPR cap 128 -> spill). 256 threads only.
//  * Random 4B scatter = 64B-line write amplification; fixed by LDS-staged
//    bucket sort (R13).
//  * R16: k_gather packed fp32 (v_pk_fma_f32), LDS transpose epilogue
//    reduce, 32-bit gather offsets. 98.7 -> <86us.
//  * R17: k_mlp per-wave 16-row tile, 4x4/thread, weights streamed from
//    global/L1, barrier-free (lgkmcnt fences only). 87 -> <73us.
//  * R18: k_gather 2 nodes/wave + padded LDS transpose.
//  * R19 FAILED: k_epi FULL global-weight streaming: 70->95us.
//  * R20: packed fp32 in k_epi/k_mlp GEMM cores -> both <68us. 426->398.
//  * R21 FAILED: k_gather 32-row register batching: occupancy 62->29%.
//    k_gather pinned at ~3.5TB/s random-gather BW. REVERTED.
//  * R22: k_bscatter2 wave-striped bucket drain: 398->374.6.
//  * R23: SCT 6272, packed u32 pairs, fill3 LDS staging: 374.6->370.5.
//  * R24 FAILED: wx streamed + merged W0/W1: 70->74.8 (VALUBusy 66->43 =
//    R19's streaming signature; THIRD confirmation k_epi needs ALL weights
//    in LDS). Merge not implicated by counters.
//  * R25 (this round): decomposition -- wx back in LDS (exact R23 staging,
//    68.6KB), KEEP only the merged W0/W1 dual-accumulator core (halves
//    A-tile ds_reads for those GEMMs, doubles indep chains). Bit-identical.

#define SCT 6272     // edges per scatter tile: 256 tiles exactly
#define F3CAP 12288  // fill3 LDS staging capacity (mean bucket 8163, sd~90)

typedef float v2f __attribute__((ext_vector_type(2)));

__device__ __forceinline__ v2f v2fma(v2f a, v2f b, v2f c) {
#if __has_builtin(__builtin_elementwise_fma)
    return __builtin_elementwise_fma(a, b, c);
#else
    v2f r; r.x = fmaf(a.x, b.x, c.x); r.y = fmaf(a.y, b.y, c.y); return r;
#endif
}

// wave-level LDS fence: orders compiler memory ops + drains DS queue.
__device__ __forceinline__ void lds_fence() {
    asm volatile("s_waitcnt lgkmcnt(0)" ::: "memory");
}

__device__ __forceinline__ float fast_tanh(float x) {
    x = fminf(fmaxf(x, -15.f), 15.f);
    float e = __expf(2.f * x);
    return (e - 1.f) * __frcp_rn(e + 1.f);
}

// 256 threads: stage 32 rows x 64 cols (8 floats/thread) -- used by k_epi
__device__ __forceinline__ void load_rows32(const float* __restrict__ src, int row0, int n,
                                            float (*dst)[68], int t)
{
    int e = t * 8;
    int r = e >> 6, i = e & 63;
    int grow = row0 + r;
    float4 v0 = make_float4(0.f, 0.f, 0.f, 0.f), v1 = v0;
    if (grow < n) {
        const float* p = src + (size_t)grow * 64 + i;
        v0 = *(const float4*)p;
        v1 = *(const float4*)(p + 4);
    }
    *(float4*)&dst[r][i]     = v0;
    *(float4*)&dst[r][i + 4] = v1;
}

// ---- R20 packed core, weights from LDS (k_epi wx): 2 rows x 4 cols/thread,
// 16 pk_fma per 4-k step. Same k-order -> bit-identical. ----
__device__ __forceinline__ void gemm_core_pk(const float (*in)[68], const float* w,
                                             const float* b, int rg, int cg,
                                             float (&o0)[4], float (&o1)[4])
{
    float bb0 = b[4*cg], bb1 = b[4*cg+1], bb2 = b[4*cg+2], bb3 = b[4*cg+3];
    v2f acc0a = {bb0, bb1}, acc0b = {bb2, bb3};
    v2f acc1a = acc0a, acc1b = acc0b;
    const int r0 = 2 * rg, r1 = 2 * rg + 1;
#pragma unroll
    for (int i = 0; i < 64; i += 4) {
        float4 a0 = *(const float4*)&in[r0][i];
        float4 a1 = *(const float4*)&in[r1][i];
        const float* q = &w[i * 64 + 4 * cg];
        v2f q0a = *(const v2f*)(q),       q0b = *(const v2f*)(q + 2);
        v2f q1a = *(const v2f*)(q + 64),  q1b = *(const v2f*)(q + 66);
        v2f q2a = *(const v2f*)(q + 128), q2b = *(const v2f*)(q + 130);
        v2f q3a = *(const v2f*)(q + 192), q3b = *(const v2f*)(q + 194);
        v2f s;
        s = (v2f){a0.x, a0.x}; acc0a = v2fma(s, q0a, acc0a); acc0b = v2fma(s, q0b, acc0b);
        s = (v2f){a0.y, a0.y}; acc0a = v2fma(s, q1a, acc0a); acc0b = v2fma(s, q1b, acc0b);
        s = (v2f){a0.z, a0.z}; acc0a = v2fma(s, q2a, acc0a); acc0b = v2fma(s, q2b, acc0b);
        s = (v2f){a0.w, a0.w}; acc0a = v2fma(s, q3a, acc0a); acc0b = v2fma(s, q3b, acc0b);
        s = (v2f){a1.x, a1.x}; acc1a = v2fma(s, q0a, acc1a); acc1b = v2fma(s, q0b, acc1b);
        s = (v2f){a1.y, a1.y}; acc1a = v2fma(s, q1a, acc1a); acc1b = v2fma(s, q1b, acc1b);
        s = (v2f){a1.z, a1.z}; acc1a = v2fma(s, q2a, acc1a); acc1b = v2fma(s, q2b, acc1b);
        s = (v2f){a1.w, a1.w}; acc1a = v2fma(s, q3a, acc1a); acc1b = v2fma(s, q3b, acc1b);
    }
    o0[0] = acc0a.x; o0[1] = acc0a.y; o0[2] = acc0b.x; o0[3] = acc0b.y;
    o1[0] = acc1a.x; o1[1] = acc1a.y; o1[2] = acc1b.x; o1[3] = acc1b.y;
}

// ---- R25 merged dual-weight core (k_epi W0+W1, both from LDS): reads
// each A float4 ONCE, feeds both accumulator sets. Per-output k-order
// identical to two gemm_core_pk calls -> bit-identical results. ----
__device__ __forceinline__ void gemm2_core_pk(const float (*in)[68],
                                              const float* w0, const float* w1,
                                              const float* c0, const float* c1,
                                              int rg, int cg,
                                              float (&x0)[4], float (&x1)[4],
                                              float (&y0)[4], float (&y1)[4])
{
    v2f A0a = {c0[4*cg], c0[4*cg+1]}, A0b = {c0[4*cg+2], c0[4*cg+3]};
    v2f A1a = A0a, A1b = A0b;
    v2f B0a = {c1[4*cg], c1[4*cg+1]}, B0b = {c1[4*cg+2], c1[4*cg+3]};
    v2f B1a = B0a, B1b = B0b;
    const int r0 = 2 * rg, r1 = 2 * rg + 1;
#pragma unroll
    for (int i = 0; i < 64; i += 4) {
        float4 a0 = *(const float4*)&in[r0][i];
        float4 a1 = *(const float4*)&in[r1][i];
        const float* q = &w0[i * 64 + 4 * cg];
        const float* p = &w1[i * 64 + 4 * cg];
        v2f q0a = *(const v2f*)(q),       q0b = *(const v2f*)(q + 2);
        v2f q1a = *(const v2f*)(q + 64),  q1b = *(const v2f*)(q + 66);
        v2f q2a = *(const v2f*)(q + 128), q2b = *(const v2f*)(q + 130);
        v2f q3a = *(const v2f*)(q + 192), q3b = *(const v2f*)(q + 194);
        v2f s;
        s = (v2f){a0.x, a0.x}; A0a = v2fma(s, q0a, A0a); A0b = v2fma(s, q0b, A0b);
        s = (v2f){a0.y, a0.y}; A0a = v2fma(s, q1a, A0a); A0b = v2fma(s, q1b, A0b);
        s = (v2f){a0.z, a0.z}; A0a = v2fma(s, q2a, A0a); A0b = v2fma(s, q2b, A0b);
        s = (v2f){a0.w, a0.w}; A0a = v2fma(s, q3a, A0a); A0b = v2fma(s, q3b, A0b);
        s = (v2f){a1.x, a1.x}; A1a = v2fma(s, q0a, A1a); A1b = v2fma(s, q0b, A1b);
        s = (v2f){a1.y, a1.y}; A1a = v2fma(s, q1a, A1a); A1b = v2fma(s, q1b, A1b);
        s = (v2f){a1.z, a1.z}; A1a = v2fma(s, q2a, A1a); A1b = v2fma(s, q2b, A1b);
        s = (v2f){a1.w, a1.w}; A1a = v2fma(s, q3a, A1a); A1b = v2fma(s, q3b, A1b);
        v2f p0a = *(const v2f*)(p),       p0b = *(const v2f*)(p + 2);
        v2f p1a = *(const v2f*)(p + 64),  p1b = *(const v2f*)(p + 66);
        v2f p2a = *(const v2f*)(p + 128), p2b = *(const v2f*)(p + 130);
        v2f p3a = *(const v2f*)(p + 192), p3b = *(const v2f*)(p + 194);
        s = (v2f){a0.x, a0.x}; B0a = v2fma(s, p0a, B0a); B0b = v2fma(s, p0b, B0b);
        s = (v2f){a0.y, a0.y}; B0a = v2fma(s, p1a, B0a); B0b = v2fma(s, p1b, B0b);
        s = (v2f){a0.z, a0.z}; B0a = v2fma(s, p2a, B0a); B0b = v2fma(s, p2b, B0b);
        s = (v2f){a0.w, a0.w}; B0a = v2fma(s, p3a, B0a); B0b = v2fma(s, p3b, B0b);
        s = (v2f){a1.x, a1.x}; B1a = v2fma(s, p0a, B1a); B1b = v2fma(s, p0b, B1b);
        s = (v2f){a1.y, a1.y}; B1a = v2fma(s, p1a, B1a); B1b = v2fma(s, p1b, B1b);
        s = (v2f){a1.z, a1.z}; B1a = v2fma(s, p2a, B1a); B1b = v2fma(s, p2b, B1b);
        s = (v2f){a1.w, a1.w}; B1a = v2fma(s, p3a, B1a); B1b = v2fma(s, p3b, B1b);
    }
    x0[0] = A0a.x; x0[1] = A0a.y; x0[2] = A0b.x; x0[3] = A0b.y;
    x1[0] = A1a.x; x1[1] = A1a.y; x1[2] = A1b.x; x1[3] = A1b.y;
    y0[0] = B0a.x; y0[1] = B0a.y; y0[2] = B0b.x; y0[3] = B0b.y;
    y1[0] = B1a.x; y1[1] = B1a.y; y1[2] = B1b.x; y1[3] = B1b.y;
}

// ---- R20 packed R17 core: per-wave tile, 4 rows x 4 cols/thread, weights
// from global/L1; unroll 2 bounds in-flight loads (full unroll = spill). ----
__device__ __forceinline__ void gemm4_pk(const float (*in)[68], const float* __restrict__ w,
                                         const float* b, int rgs, int cg,
                                         float (&out)[4][4])
{
    float bb0 = b[4*cg], bb1 = b[4*cg+1], bb2 = b[4*cg+2], bb3 = b[4*cg+3];
    v2f ba = {bb0, bb1}, bbv = {bb2, bb3};
    v2f acc[4][2];
#pragma unroll
    for (int r = 0; r < 4; r++) { acc[r][0] = ba; acc[r][1] = bbv; }
    const float* wp = w + 4 * cg;
    const int r0 = 4 * rgs;
#pragma unroll 2
    for (int i = 0; i < 64; i += 4) {
        v2f q0a = *(const v2f*)(wp + (i + 0) * 64), q0b = *(const v2f*)(wp + (i + 0) * 64 + 2);
        v2f q1a = *(const v2f*)(wp + (i + 1) * 64), q1b = *(const v2f*)(wp + (i + 1) * 64 + 2);
        v2f q2a = *(const v2f*)(wp + (i + 2) * 64), q2b = *(const v2f*)(wp + (i + 2) * 64 + 2);
        v2f q3a = *(const v2f*)(wp + (i + 3) * 64), q3b = *(const v2f*)(wp + (i + 3) * 64 + 2);
#pragma unroll
        for (int r = 0; r < 4; r++) {
            float4 a = *(const float4*)&in[r0 + r][i];
            v2f s;
            s = (v2f){a.x, a.x}; acc[r][0] = v2fma(s, q0a, acc[r][0]); acc[r][1] = v2fma(s, q0b, acc[r][1]);
            s = (v2f){a.y, a.y}; acc[r][0] = v2fma(s, q1a, acc[r][0]); acc[r][1] = v2fma(s, q1b, acc[r][1]);
            s = (v2f){a.z, a.z}; acc[r][0] = v2fma(s, q2a, acc[r][0]); acc[r][1] = v2fma(s, q2b, acc[r][1]);
            s = (v2f){a.w, a.w}; acc[r][0] = v2fma(s, q3a, acc[r][0]); acc[r][1] = v2fma(s, q3b, acc[r][1]);
        }
    }
#pragma unroll
    for (int r = 0; r < 4; r++) {
        out[r][0] = acc[r][0].x; out[r][1] = acc[r][0].y;
        out[r][2] = acc[r][1].x; out[r][3] = acc[r][1].y;
    }
}

// ---------------- CSR build: LDS-staged bucket sort (R13/R22/R23) ----------------

__global__ __launch_bounds__(256) void k_bhist(const int* __restrict__ col,
                                               int* __restrict__ bhist, int e)
{
    __shared__ int hist[256];
    int t = threadIdx.x;
    hist[t] = 0;
    __syncthreads();
    int base = blockIdx.x * SCT;
    int end = min(e, base + SCT);
    for (int i = base + t; i < end; i += 256)
        atomicAdd(&hist[col[i] >> 9], 1);
    __syncthreads();
    if (hist[t]) atomicAdd(&bhist[t], hist[t]);
}

__global__ __launch_bounds__(256) void k_bscan(const int* __restrict__ bhist,
                                               int* __restrict__ bbase, int* __restrict__ bcur)
{
    __shared__ int s[256];
    int t = threadIdx.x;
    int v = bhist[t];
    s[t] = v;
    __syncthreads();
    for (int d = 1; d < 256; d <<= 1) {
        int u = (t >= d) ? s[t - d] : 0;
        __syncthreads();
        s[t] += u;
        __syncthreads();
    }
    int b = s[t] - v;
    bbase[t] = b;
    bcur[t] = b;
}

// R23: pairs packed as u32: row in [0,17), (col&511) in [17,26).
__global__ __launch_bounds__(256) void k_bscatter2(const int* __restrict__ row,
    const int* __restrict__ col, int* __restrict__ bcur,
    unsigned* __restrict__ pairs, int e, int nbk)
{
    __shared__ int hist[256], lcur[256], gb[256], s[256];
    __shared__ unsigned buf[SCT];
    int t = threadIdx.x;
    int base = blockIdx.x * SCT;
    int end = min(e, base + SCT);
    hist[t] = 0;
    __syncthreads();
    for (int i = base + t; i < end; i += 256)
        atomicAdd(&hist[col[i] >> 9], 1);
    __syncthreads();
    int v = hist[t];
    s[t] = v;
    __syncthreads();
    for (int d = 1; d < 256; d <<= 1) {
        int u = (t >= d) ? s[t - d] : 0;
        __syncthreads();
        s[t] += u;
        __syncthreads();
    }
    lcur[t] = s[t] - v;
    __syncthreads();
    for (int i = base + t; i < end; i += 256) {
        int c = col[i];
        int slot = atomicAdd(&lcur[c >> 9], 1);
        buf[slot] = (unsigned)row[i] | ((unsigned)(c & 511) << 17);
    }
    if (v > 0) gb[t] = atomicAdd(&bcur[t], v);
    __syncthreads();
    // R22: stripe buckets across the 4 waves (disjoint buckets, read-only
    // metadata after the barrier).
    int wv = t >> 6, lane = t & 63;
    for (int b = wv; b < nbk; b += 4) {
        int cnt = hist[b];
        if (cnt == 0) continue;
        int lo = s[b] - cnt;
        int go = gb[b];
        for (int j = lane; j < cnt; j += 64)
            pairs[go + j] = buf[lo + j];
    }
}

__global__ __launch_bounds__(256) void k_fill3(const unsigned* __restrict__ pairs,
    const int* __restrict__ bbase, const int* __restrict__ bhist,
    int* __restrict__ arr, int* __restrict__ csr, int n)
{
    __shared__ int nh[512], nc[512], s[256];
    __shared__ unsigned sbuf[F3CAP];      // R23: stage packed pairs once
    int b = blockIdx.x, t = threadIdx.x;
    int pbase = bbase[b];
    int cnt = bhist[b];
    int nodebase = b << 9;
    nh[t] = 0; nh[t + 256] = 0;
    __syncthreads();
    for (int i = t; i < cnt; i += 256) {
        unsigned pv = pairs[pbase + i];
        if (i < F3CAP) sbuf[i] = pv;
        atomicAdd(&nh[pv >> 17], 1);
    }
    __syncthreads();
    int v0 = nh[2 * t], v1 = nh[2 * t + 1];
    int sum = v0 + v1;
    s[t] = sum;
    __syncthreads();
    for (int d = 1; d < 256; d <<= 1) {
        int u = (t >= d) ? s[t - d] : 0;
        __syncthreads();
        s[t] += u;
        __syncthreads();
    }
    int excl = s[t] - sum;
    int n0 = nodebase + 2 * t, n1 = n0 + 1;
    nc[2 * t]     = pbase + excl;
    nc[2 * t + 1] = pbase + excl + v0;
    if (n0 < n) arr[n0] = pbase + excl + v0;
    if (n1 < n) arr[n1] = pbase + excl + v0 + v1;
    __syncthreads();
    for (int i = t; i < cnt; i += 256) {
        unsigned pv = (i < F3CAP) ? sbuf[i] : pairs[pbase + i];
        int p = atomicAdd(&nc[pv >> 17], 1);
        csr[p] = (int)(pv & 0x1FFFFu);
    }
}

// ---------------- weight precombination ----------------
// pre layout (floats): W0[4096] | W1[4096] | c0[64]@8192 | c1[64]@8256 |
//                      u0[128]@8320 | u1[128]@8448 | v[4]@8576

__global__ __launch_bounds__(256) void k_pre(
    const float* __restrict__ wg1, const float* __restrict__ bg1,
    const float* __restrict__ wg2, const float* __restrict__ bg2,
    const float* __restrict__ wf,  const float* __restrict__ bf,
    const float* __restrict__ wc,  float* __restrict__ pre)
{
    __shared__ float wfs[4096];
    __shared__ float wcs[128];
    int t = threadIdx.x;
    for (int i = t; i < 4096; i += 256) wfs[i] = wf[i];
    if (t < 128) wcs[t] = wc[t];
    __syncthreads();
    int i = t & 63, jb = (t >> 6) * 16;
    float acc0[16], acc1[16];
#pragma unroll
    for (int j = 0; j < 16; j++) { acc0[j] = 0.f; acc1[j] = 0.f; }
#pragma unroll 1
    for (int k = 0; k < 64; k++) {
        float a = wg1[i * 64 + k];
        float b = wg2[i * 64 + k];
#pragma unroll
        for (int j = 0; j < 16; j++) {
            float w = wfs[k * 64 + jb + j];
            acc0[j] = fmaf(a, w, acc0[j]);
            acc1[j] = fmaf(b, w, acc1[j]);
        }
    }
#pragma unroll
    for (int j = 0; j < 16; j++) {
        pre[i * 64 + jb + j]        = acc0[j];
        pre[4096 + i * 64 + jb + j] = acc1[j];
    }
    if (t < 64) {
        float s0 = bf[t], s1 = bf[t];
#pragma unroll 1
        for (int m = 0; m < 64; m++) {
            s0 = fmaf(bg1[m], wfs[m * 64 + t], s0);
            s1 = fmaf(bg2[m], wfs[m * 64 + t], s1);
        }
        pre[8192 + t] = s0;
        pre[8256 + t] = s1;
        float u00 = 0.f, u01 = 0.f, u10 = 0.f, u11 = 0.f;
#pragma unroll 1
        for (int m = 0; m < 64; m++) {
            float g1 = wg1[t * 64 + m], g2 = wg2[t * 64 + m];
            u00 = fmaf(g1, wcs[m * 2 + 0], u00);
            u01 = fmaf(g1, wcs[m * 2 + 1], u01);
            u10 = fmaf(g2, wcs[m * 2 + 0], u10);
            u11 = fmaf(g2, wcs[m * 2 + 1], u11);
        }
        pre[8320 + t * 2]     = u00;
        pre[8320 + t * 2 + 1] = u01;
        pre[8448 + t * 2]     = u10;
        pre[8448 + t * 2 + 1] = u11;
    }
    if (t == 0) {
        float v00 = 0.f, v01 = 0.f, v10 = 0.f, v11 = 0.f;
#pragma unroll 1
        for (int m = 0; m < 64; m++) {
            v00 = fmaf(bg1[m], wcs[m * 2 + 0], v00);
            v01 = fmaf(bg1[m], wcs[m * 2 + 1], v01);
            v10 = fmaf(bg2[m], wcs[m * 2 + 0], v10);
            v11 = fmaf(bg2[m], wcs[m * 2 + 1], v11);
        }
        pre[8576] = v00; pre[8577] = v01; pre[8578] = v10; pre[8579] = v11;
    }
}

// ---------------- node MLP: per-wave 16-row tile, barrier-free (R17, packed R20) ----------------

__global__ __launch_bounds__(256) void k_mlp(const float* __restrict__ x,
    const float* __restrict__ w1, const float* __restrict__ b1,
    const float* __restrict__ w2, const float* __restrict__ b2,
    const float* __restrict__ w3, const float* __restrict__ b3,
    const int* __restrict__ arr, float* __restrict__ h,
    float2* __restrict__ nrm2, int n)
{
    __shared__ float b1s[64], b2s[64], b3s[64];
    __shared__ float xs[4][16][68];          // one 16-row slice per wave
    int t = threadIdx.x;
    if (t < 64) { b1s[t] = b1[t]; b2s[t] = b2[t]; b3s[t] = b3[t]; }
    __syncthreads();                          // once, for biases only
    int wv = t >> 6, lane = t & 63;
    int cg = lane & 15, rgs = lane >> 4;      // thread: rows 4*rgs..+3, cols 4*cg..+3
    int row0 = blockIdx.x * 64 + wv * 16;     // this wave's 16 rows
    float (*ws)[68] = xs[wv];

    // stage: lane stages row lane>>2, cols (lane&3)*16 (wave reads 4KB contiguous)
    {
        int r = lane >> 2, c = (lane & 3) * 16;
        int grow = row0 + r;
        float4 v0 = make_float4(0.f,0.f,0.f,0.f), v1 = v0, v2 = v0, v3 = v0;
        if (grow < n) {
            const float* p = x + (size_t)grow * 64 + c;
            v0 = *(const float4*)p;       v1 = *(const float4*)(p + 4);
            v2 = *(const float4*)(p + 8); v3 = *(const float4*)(p + 12);
        }
        *(float4*)&ws[r][c]      = v0; *(float4*)&ws[r][c + 4]  = v1;
        *(float4*)&ws[r][c + 8]  = v2; *(float4*)&ws[r][c + 12] = v3;
    }
    lds_fence();

    float acc[4][4];
    // layer 1: read xs slice, relu, overwrite in place (lockstep: all wave
    // reads precede the write instructions; fences order DS completion)
    gemm4_pk(ws, w1, b1s, rgs, cg, acc);
    lds_fence();
#pragma unroll
    for (int r = 0; r < 4; r++)
        *(float4*)&ws[4 * rgs + r][4 * cg] =
            make_float4(fmaxf(acc[r][0], 0.f), fmaxf(acc[r][1], 0.f),
                        fmaxf(acc[r][2], 0.f), fmaxf(acc[r][3], 0.f));
    lds_fence();
    // layer 2
    gemm4_pk(ws, w2, b2s, rgs, cg, acc);
    lds_fence();
#pragma unroll
    for (int r = 0; r < 4; r++)
        *(float4*)&ws[4 * rgs + r][4 * cg] =
            make_float4(fmaxf(acc[r][0], 0.f), fmaxf(acc[r][1], 0.f),
                        fmaxf(acc[r][2], 0.f), fmaxf(acc[r][3], 0.f));
    lds_fence();
    // layer 3 + fused per-node scalars
    gemm4_pk(ws, w3, b3s, rgs, cg, acc);

    int r0g = row0 + 4 * rgs;
    float sr[4];
#pragma unroll
    for (int r = 0; r < 4; r++) {
        int grow = r0g + r;
        if (grow < n)
            *(float4*)&h[(size_t)grow * 64 + 4 * cg] =
                make_float4(acc[r][0], acc[r][1], acc[r][2], acc[r][3]);
        sr[r] = acc[r][0]*acc[r][0] + acc[r][1]*acc[r][1]
              + acc[r][2]*acc[r][2] + acc[r][3]*acc[r][3];
    }
#pragma unroll
    for (int d = 1; d < 16; d <<= 1) {
#pragma unroll
        for (int r = 0; r < 4; r++) sr[r] += __shfl_xor(sr[r], d, 64);
    }
    if (cg == 0) {
#pragma unroll
        for (int r = 0; r < 4; r++) {
            int grow = r0g + r;
            if (grow < n) {
                int st = (grow == 0) ? 0 : arr[grow - 1];
                nrm2[grow] = make_float2(1.0f / (sqrtf(sr[r]) + 1e-12f),
                                         rsqrtf((float)(arr[grow] - st + 1)));
            }
        }
    }
}

// ---------------- edge pass: 2 nodes/wave, per half 4 edge-groups x 8 lanes (R18/R20) ----------------

__global__ __launch_bounds__(256) void k_gather(const float* __restrict__ h,
    const int* __restrict__ arr, const int* __restrict__ csr,
    const float2* __restrict__ nrm2, const float* __restrict__ beta_p,
    const float* __restrict__ wc,
    float* __restrict__ agg, float2* __restrict__ yp, int n)
{
    // [wave][g][sub][col+pad]: pad 66 -> write banks (4g+2sub+8s)%32 cover
    // all 32 banks at 8 words/bank (floor). 16.9KB total.
    __shared__ float reda[4][4][2][66];
    __shared__ float redn[4][4][2][66];
    int wv = threadIdx.x >> 6;
    int lane = threadIdx.x & 63;
    int sub = lane >> 5;              // which node in this wave
    int l32 = lane & 31;              // lane within half
    int g = l32 >> 3, s = l32 & 7;    // 4 groups x 8 lanes per half
    int base = sub << 5;              // absolute lane offset of this half
    int node = blockIdx.x * 8 + wv * 2 + sub;
    bool valid = node < n;
    int nd = valid ? node : 0;
    float beta = beta_p[0];
    const char* hb = (const char*)h;

    // self row: lane covers cols 8s..8s+7 (32-bit byte offset -> SADDR loads)
    unsigned selfoff = ((unsigned)nd << 8) + ((unsigned)s << 5);
    float4 hA = *(const float4*)(hb + selfoff);
    float4 hB = *(const float4*)(hb + selfoff + 16);
    v2f hc0 = {hA.x, hA.y}, hc1 = {hA.z, hA.w};
    v2f hc2 = {hB.x, hB.y}, hc3 = {hB.z, hB.w};

    v2f sv = hc0 * hc0;
    sv = v2fma(hc1, hc1, sv); sv = v2fma(hc2, hc2, sv); sv = v2fma(hc3, hc3, sv);
    float ss = sv.x + sv.y;
#pragma unroll
    for (int d = 1; d < 8; d <<= 1) ss += __shfl_xor(ss, d, 64);   // within group
    float2 ncv = nrm2[nd];
    float rnc = ncv.x, dc = ncv.y;
    float brn = beta * rnc;                 // hoisted: w = exp(brn * p * rnr)
    float wself = __expf(brn * ss * rnc);

    v2f a0 = {0.f,0.f}, a1 = {0.f,0.f}, a2 = {0.f,0.f}, a3 = {0.f,0.f};
    v2f n0 = {0.f,0.f}, n1 = {0.f,0.f}, n2 = {0.f,0.f}, n3 = {0.f,0.f};
    float denom = 0.f;
    if (g == 0) {                           // self-loop contribution, once per half
        v2f dcv = {dc, dc}, wsv = {wself, wself};
        a0 = dcv * hc0; a1 = dcv * hc1; a2 = dcv * hc2; a3 = dcv * hc3;
        n0 = wsv * hc0; n1 = wsv * hc1; n2 = wsv * hc2; n3 = wsv * hc3;
        denom = wself;
    }

    int start = (!valid || nd == 0) ? 0 : arr[nd - 1];
    int end = valid ? arr[nd] : 0;
#pragma unroll 1
    for (int k0 = start; k0 < end; k0 += 32) {
        int m = min(32, end - k0);
        int idx = 0; float rv = 0.f, dv = 0.f;
        if (l32 < m) {
            idx = csr[k0 + l32];
            float2 ndv = nrm2[idx];
            rv = ndv.x; dv = ndv.y;
        }
        int ei = __shfl(idx, base + g, 64);
        unsigned eoff = ((unsigned)ei << 8) + ((unsigned)s << 5);
        float4 cA = *(const float4*)(hb + eoff);
        float4 cB = *(const float4*)(hb + eoff + 16);
#pragma unroll 1
        for (int k = 0; k < m; k += 4) {
            float4 fA = cA, fB = cB;
            if (k + 4 < m) {
                int e2 = __shfl(idx, base + k + 4 + g, 64);
                unsigned off2 = ((unsigned)e2 << 8) + ((unsigned)s << 5);
                cA = *(const float4*)(hb + off2);
                cB = *(const float4*)(hb + off2 + 16);
            }
            float rnr = __shfl(rv, base + k + g, 64);
            float dvr = __shfl(dv, base + k + g, 64);
            v2f f0 = {fA.x, fA.y}, f1 = {fA.z, fA.w};
            v2f f2 = {fB.x, fB.y}, f3 = {fB.z, fB.w};
            // dot(h[src], h[dst]) over this lane's 8 cols, packed
            v2f ps = f0 * hc0;
            ps = v2fma(f1, hc1, ps); ps = v2fma(f2, hc2, ps); ps = v2fma(f3, hc3, ps);
            float p = ps.x + ps.y;
#pragma unroll
            for (int d = 1; d < 8; d <<= 1) p += __shfl_xor(p, d, 64);
            bool act = (k + g) < m;
            float w   = act ? __expf(brn * p * rnr) : 0.f;
            float dve = act ? dvr : 0.f;
            v2f wsp = {w, w}, dsp = {dve, dve};
            a0 = v2fma(dsp, f0, a0); a1 = v2fma(dsp, f1, a1);
            a2 = v2fma(dsp, f2, a2); a3 = v2fma(dsp, f3, a3);
            n0 = v2fma(wsp, f0, n0); n1 = v2fma(wsp, f1, n1);
            n2 = v2fma(wsp, f2, n2); n3 = v2fma(wsp, f3, n3);
            denom += w;
        }
    }

    // ---- cross-group reduce via padded LDS transpose ----
    {
        float* wa = &reda[wv][g][sub][8 * s];
        float* wn = &redn[wv][g][sub][8 * s];
        *(float4*)wa       = make_float4(a0.x, a0.y, a1.x, a1.y);
        *(float4*)(wa + 4) = make_float4(a2.x, a2.y, a3.x, a3.y);
        *(float4*)wn       = make_float4(n0.x, n0.y, n1.x, n1.y);
        *(float4*)(wn + 4) = make_float4(n2.x, n2.y, n3.x, n3.y);
    }
    lds_fence();
    // lane (sub,l32) sums cols l32 and l32+32 of its node across the 4 groups
    float a_lo, a_hi, n_lo, n_hi;
    {
        const float* r0p = &reda[wv][0][sub][0];
        const float* r1p = &redn[wv][0][sub][0];
        float t0 = r0p[l32]       + r0p[132 + l32];
        float t1 = r0p[264 + l32] + r0p[396 + l32];
        float t2 = r0p[l32 + 32]       + r0p[132 + l32 + 32];
        float t3 = r0p[264 + l32 + 32] + r0p[396 + l32 + 32];
        a_lo = t0 + t1; a_hi = t2 + t3;
        float u0 = r1p[l32]       + r1p[132 + l32];
        float u1 = r1p[264 + l32] + r1p[396 + l32];
        float u2 = r1p[l32 + 32]       + r1p[132 + l32 + 32];
        float u3 = r1p[264 + l32 + 32] + r1p[396 + l32 + 32];
        n_lo = u0 + u1; n_hi = u2 + u3;
    }
    if (valid) {
        agg[(size_t)node * 64 + l32]      = dc * a_lo;
        agg[(size_t)node * 64 + l32 + 32] = dc * a_hi;
    }

    // denom varies only across g within the half: 2-stage reduce
    denom += __shfl_xor(denom, 8, 64);
    denom += __shfl_xor(denom, 16, 64);

    // classifier contribution of h1: lane owns cols l32 and l32+32
    float2 w_lo = *(const float2*)(wc + 128 + 2 * l32);
    float2 w_hi = *(const float2*)(wc + 128 + 2 * (l32 + 32));
    float cx = n_lo * w_lo.x + n_hi * w_hi.x;
    float cy = n_lo * w_lo.y + n_hi * w_hi.y;
#pragma unroll
    for (int d = 1; d < 32; d <<= 1) { cx += __shfl_xor(cx, d, 64); cy += __shfl_xor(cy, d, 64); }
    if (l32 == 0 && valid) {
        float inv = 1.0f / denom;
        yp[node] = make_float2(cx * inv, cy * inv);
    }
}

// ---------------- epilogue: ALL weights in LDS (R23), merged W0/W1 core (R25) ----------------

__global__ __launch_bounds__(256) void k_epi(const float* __restrict__ agg,
    const float* __restrict__ hbuf, const float2* __restrict__ yp,
    const float* __restrict__ pre, const float* __restrict__ wx,
    const float* __restrict__ bx, const float* __restrict__ bc,
    float* __restrict__ y, int n, int ntiles)
{
    __shared__ float W0s[4096], W1s[4096], wxs[4096];
    __shared__ float c0s[64], c1s[64], bxs[64], us[256], vs[4], bcs[2];
    __shared__ float A[32][68], H[32][68];
    int t = threadIdx.x;
    for (int i = t; i < 4096; i += 256) { W0s[i] = pre[i]; W1s[i] = pre[4096 + i]; wxs[i] = wx[i]; }
    if (t < 64) { c0s[t] = pre[8192 + t]; c1s[t] = pre[8256 + t]; bxs[t] = bx[t]; }
    us[t] = pre[8320 + t];
    if (t < 4) vs[t] = pre[8576 + t];
    if (t < 2) bcs[t] = bc[t];
    __syncthreads();
    int cg = t & 15, rg = t >> 4;
    for (int tile = blockIdx.x; tile < ntiles; tile += gridDim.x) {
        int row0 = tile * 32;
        load_rows32(agg,  row0, n, A, t);
        load_rows32(hbuf, row0, n, H, t);
        __syncthreads();
        int r0g = row0 + 2 * rg, r1g = r0g + 1;
        float xp0[4], xp1[4];
        gemm_core_pk(H, wxs, bxs, rg, cg, xp0, xp1);
#pragma unroll
        for (int j = 0; j < 4; j++) { xp0[j] = fast_tanh(xp0[j]); xp1[j] = fast_tanh(xp1[j]); }
        float a0[4], a1[4], b0[4], b1[4];
        gemm2_core_pk(A, W0s, W1s, c0s, c1s, rg, cg, a0, a1, b0, b1);  // R25: merged
        float l00 = 0.f, l01 = 0.f, l10 = 0.f, l11 = 0.f;
#pragma unroll
        for (int j = 0; j < 4; j++) {
            l00 = fmaf(fast_tanh(a0[j]), xp0[j], l00);
            l01 = fmaf(fast_tanh(a1[j]), xp1[j], l01);
            l10 = fmaf(fast_tanh(b0[j]), xp0[j], l10);
            l11 = fmaf(fast_tanh(b1[j]), xp1[j], l11);
        }
        float4 av0 = *(const float4*)&A[2 * rg][4 * cg];
        float4 av1 = *(const float4*)&A[2 * rg + 1][4 * cg];
        float za0=0.f, za1=0.f, zb0=0.f, zb1=0.f;
        float zc0=0.f, zc1=0.f, zd0=0.f, zd1=0.f;
#pragma unroll
        for (int j = 0; j < 4; j++) {
            int k = 4 * cg + j;
            float u0c0 = us[k * 2], u0c1 = us[k * 2 + 1];
            float u1c0 = us[128 + k * 2], u1c1 = us[128 + k * 2 + 1];
            float p0 = (&av0.x)[j], p1 = (&av1.x)[j];
            za0 = fmaf(p0, u0c0, za0); za1 = fmaf(p0, u0c1, za1);
            zb0 = fmaf(p0, u1c0, zb0); zb1 = fmaf(p0, u1c1, zb1);
            zc0 = fmaf(p1, u0c0, zc0); zc1 = fmaf(p1, u0c1, zc1);
            zd0 = fmaf(p1, u1c0, zd0); zd1 = fmaf(p1, u1c1, zd1);
        }
#pragma unroll
        for (int d = 1; d < 16; d <<= 1) {
            l00 += __shfl_xor(l00, d, 64); l01 += __shfl_xor(l01, d, 64);
            l10 += __shfl_xor(l10, d, 64); l11 += __shfl_xor(l11, d, 64);
            za0 += __shfl_xor(za0, d, 64); za1 += __shfl_xor(za1, d, 64);
            zb0 += __shfl_xor(zb0, d, 64); zb1 += __shfl_xor(zb1, d, 64);
            zc0 += __shfl_xor(zc0, d, 64); zc1 += __shfl_xor(zc1, d, 64);
            zd0 += __shfl_xor(zd0, d, 64); zd1 += __shfl_xor(zd1, d, 64);
        }
        if (cg == 0) {
            if (r0g < n) {
                float mx = fmaxf(l00, l10);
                float e0 = __expf(l00 - mx), e1 = __expf(l10 - mx);
                float inv = 1.0f / (e0 + e1);
                float s0 = e0 * inv, s1 = e1 * inv;
                float2 ypv = yp[r0g];
                float y0v = s0 * (za0 + vs[0]) + s1 * (zb0 + vs[2]) + ypv.x + bcs[0];
                float y1v = s0 * (za1 + vs[1]) + s1 * (zb1 + vs[3]) + ypv.y + bcs[1];
                *(float2*)&y[(size_t)r0g * 2] = make_float2(y0v, y1v);
            }
            if (r1g < n) {
                float mx = fmaxf(l01, l11);
                float e0 = __expf(l01 - mx), e1 = __expf(l11 - mx);
                float inv = 1.0f / (e0 + e1);
                float s0 = e0 * inv, s1 = e1 * inv;
                float2 ypv = yp[r1g];
                float y0v = s0 * (zc0 + vs[0]) + s1 * (zd0 + vs[2]) + ypv.x + bcs[0];
                float y1v = s0 * (zc1 + vs[1]) + s1 * (zd1 + vs[3]) + ypv.y + bcs[1];
                *(float2*)&y[(size_t)r1g * 2] = make_float2(y0v, y1v);
            }
        }
        __syncthreads();
    }
}

extern "C" void kernel_launch(void* const* d_in, const int* in_sizes, int n_in,
                              void* d_out, int out_size, void* d_ws, size_t ws_size,
                              hipStream_t stream)
{
    const float* x    = (const float*)d_in[0];
    const int*   ei   = (const int*)d_in[1];
    const float* w1   = (const float*)d_in[2];
    const float* b1   = (const float*)d_in[3];
    const float* w2   = (const float*)d_in[4];
    const float* b2   = (const float*)d_in[5];
    const float* w3   = (const float*)d_in[6];
    const float* b3   = (const float*)d_in[7];
    const float* wg1  = (const float*)d_in[8];
    const float* bg1  = (const float*)d_in[9];
    const float* wg2  = (const float*)d_in[10];
    const float* bg2  = (const float*)d_in[11];
    const float* beta = (const float*)d_in[12];
    const float* wf   = (const float*)d_in[13];
    const float* bf   = (const float*)d_in[14];
    const float* wx   = (const float*)d_in[15];
    const float* bx   = (const float*)d_in[16];
    const float* wc   = (const float*)d_in[17];
    const float* bc   = (const float*)d_in[18];
    float* y = (float*)d_out;

    int n = in_sizes[0] / 64;     // 100000
    int e = in_sizes[1] / 2;      // 1600000
    const int* row = ei;
    const int* col = ei + e;

    // workspace ~34MB
    char* p = (char*)d_ws;
    auto alloc = [&](size_t bytes) { char* q = p; p += (bytes + 255) & ~(size_t)255; return q; };
    float*  h    = (float*)alloc((size_t)n * 64 * 4);    // 25.6MB (pairs -> h)
    int*    csr  = (int*)alloc((size_t)e * 4);           // 6.4MB
    float2* nrm2 = (float2*)alloc((size_t)n * 8);        // 0.8MB
    int*    arr  = (int*)alloc((size_t)(n + 1) * 4);     // 0.4MB
    float2* yp   = (float2*)alloc((size_t)n * 8);        // 0.8MB
    float*  pre  = (float*)alloc(8704 * 4);              // combined weights
    int*    bhist = (int*)alloc(256 * 4);
    int*    bbase = (int*)alloc(256 * 4);
    int*    bcur  = (int*)alloc(256 * 4);

    // packed pairs buffer (6.4MB) aliases h: consumed by k_fill3 before
    // k_mlp writes h.
    unsigned* pairs = (unsigned*)h;
    // agg reuses x's buffer (x dead after k_mlp; harness restores d_in).
    float* agg = (float*)d_in[0];

    int ntiles = (n + 31) / 32;            // 3125 32-row tiles (k_epi)
    int ntile64 = (n + 63) / 64;           // 1563 64-row tiles (k_mlp)
    int nbk = (n + 511) >> 9;              // 196 buckets (col>>9)
    int nsct = (e + SCT - 1) / SCT;        // 256 scatter tiles (R23)

    k_pre<<<1, 256, 0, stream>>>(wg1, bg1, wg2, bg2, wf, bf, wc, pre);
    hipMemsetAsync(bhist, 0, 256 * sizeof(int), stream);
    k_bhist<<<nsct, 256, 0, stream>>>(col, bhist, e);
    k_bscan<<<1, 256, 0, stream>>>(bhist, bbase, bcur);
    k_bscatter2<<<nsct, 256, 0, stream>>>(row, col, bcur, pairs, e, nbk);
    k_fill3<<<nbk, 256, 0, stream>>>(pairs, bbase, bhist, arr, csr, n);
    k_mlp<<<ntile64, 256, 0, stream>>>(x, w1, b1, w2, b2, w3, b3, arr, h, nrm2, n);
    k_gather<<<(n + 7) / 8, 256, 0, stream>>>(h, arr, csr, nrm2, beta, wc, agg, yp, n);
    k_epi<<<1024, 256, 0, stream>>>(agg, h, yp, pre, wx, bx, bc, y, n, ntiles);
}

// Round 11
// 370.509 us; speedup vs baseline: 1.0243x; 1.0084x over previous
//
#include <hip/hip_runtime.h>
#include <math.h>

// N=100000 nodes, E=1600000 edges, HID=64, C=2, fp32.
// Hard-won constraints (R2-R25):
//  * FULLY-unrolled global-weight loads -> VGPR hoist -> spill (R2/R3);
//    #pragma unroll 2 bounds in-flight loads.
//  * 512-thread blocks unusable (VGPR cap 128 -> spill). 256 threads only.
//  * Random 4B scatter = 64B-line write amplification; fixed by LDS-staged
//    bucket sort (R13).
//  * R16: k_gather packed fp32 (v_pk_fma_f32), LDS transpose epilogue
//    reduce, 32-bit gather offsets. 98.7 -> <86us.
//  * R17: k_mlp per-wave 16-row tile, 4x4/thread, weights streamed from
//    global/L1, barrier-free (lgkmcnt fences only). 87 -> <73us.
//  * R18: k_gather 2 nodes/wave + padded LDS transpose.
//  * R19 FAILED: k_epi FULL global-weight streaming: 70->95us.
//  * R20: packed fp32 in k_epi/k_mlp GEMM cores -> both <68us. 426->398.
//  * R21 FAILED: k_gather 32-row register batching: occupancy 62->29%.
//    k_gather pinned at ~3.5TB/s random-gather BW. REVERTED.
//  * R22: k_bscatter2 wave-striped bucket drain: 398->374.6.
//  * R23: SCT 6272, packed u32 pairs, fill3 LDS staging: 374.6->370.5.
//    == BEST KNOWN STATE ==
//  * R24 FAILED: wx streamed + merged W0/W1: 74.8us (streaming signature).
//  * R25 FAILED: merge alone: VGPR 44->88, VALUBusy 66->47, total +3.1us.
//    Both R24 halves individually refuted.
//  * R26 (this round): pure reversion to R23. Every kernel now sits at a
//    measured structural limit: k_gather latency-pinned at ~3.5TB/s random
//    gather (R18/R21 probes); k_epi LDS-weights+tile-loop optimum (R19/
//    R24/R25 probes); k_mlp R17+R20; CSR chain exhausted (R23 marginal).

#define SCT 6272     // edges per scatter tile: 256 tiles exactly
#define F3CAP 12288  // fill3 LDS staging capacity (mean bucket 8163, sd~90)

typedef float v2f __attribute__((ext_vector_type(2)));

__device__ __forceinline__ v2f v2fma(v2f a, v2f b, v2f c) {
#if __has_builtin(__builtin_elementwise_fma)
    return __builtin_elementwise_fma(a, b, c);
#else
    v2f r; r.x = fmaf(a.x, b.x, c.x); r.y = fmaf(a.y, b.y, c.y); return r;
#endif
}

// wave-level LDS fence: orders compiler memory ops + drains DS queue.
__device__ __forceinline__ void lds_fence() {
    asm volatile("s_waitcnt lgkmcnt(0)" ::: "memory");
}

__device__ __forceinline__ float fast_tanh(float x) {
    x = fminf(fmaxf(x, -15.f), 15.f);
    float e = __expf(2.f * x);
    return (e - 1.f) * __frcp_rn(e + 1.f);
}

// 256 threads: stage 32 rows x 64 cols (8 floats/thread) -- used by k_epi
__device__ __forceinline__ void load_rows32(const float* __restrict__ src, int row0, int n,
                                            float (*dst)[68], int t)
{
    int e = t * 8;
    int r = e >> 6, i = e & 63;
    int grow = row0 + r;
    float4 v0 = make_float4(0.f, 0.f, 0.f, 0.f), v1 = v0;
    if (grow < n) {
        const float* p = src + (size_t)grow * 64 + i;
        v0 = *(const float4*)p;
        v1 = *(const float4*)(p + 4);
    }
    *(float4*)&dst[r][i]     = v0;
    *(float4*)&dst[r][i + 4] = v1;
}

// ---- R20 packed core, weights from LDS (k_epi): 2 rows x 4 cols/thread,
// 16 pk_fma per 4-k step (was 32 fma). Same k-order -> bit-identical. ----
__device__ __forceinline__ void gemm_core_pk(const float (*in)[68], const float* w,
                                             const float* b, int rg, int cg,
                                             float (&o0)[4], float (&o1)[4])
{
    float bb0 = b[4*cg], bb1 = b[4*cg+1], bb2 = b[4*cg+2], bb3 = b[4*cg+3];
    v2f acc0a = {bb0, bb1}, acc0b = {bb2, bb3};
    v2f acc1a = acc0a, acc1b = acc0b;
    const int r0 = 2 * rg, r1 = 2 * rg + 1;
#pragma unroll
    for (int i = 0; i < 64; i += 4) {
        float4 a0 = *(const float4*)&in[r0][i];
        float4 a1 = *(const float4*)&in[r1][i];
        const float* q = &w[i * 64 + 4 * cg];
        v2f q0a = *(const v2f*)(q),       q0b = *(const v2f*)(q + 2);
        v2f q1a = *(const v2f*)(q + 64),  q1b = *(const v2f*)(q + 66);
        v2f q2a = *(const v2f*)(q + 128), q2b = *(const v2f*)(q + 130);
        v2f q3a = *(const v2f*)(q + 192), q3b = *(const v2f*)(q + 194);
        v2f s;
        s = (v2f){a0.x, a0.x}; acc0a = v2fma(s, q0a, acc0a); acc0b = v2fma(s, q0b, acc0b);
        s = (v2f){a0.y, a0.y}; acc0a = v2fma(s, q1a, acc0a); acc0b = v2fma(s, q1b, acc0b);
        s = (v2f){a0.z, a0.z}; acc0a = v2fma(s, q2a, acc0a); acc0b = v2fma(s, q2b, acc0b);
        s = (v2f){a0.w, a0.w}; acc0a = v2fma(s, q3a, acc0a); acc0b = v2fma(s, q3b, acc0b);
        s = (v2f){a1.x, a1.x}; acc1a = v2fma(s, q0a, acc1a); acc1b = v2fma(s, q0b, acc1b);
        s = (v2f){a1.y, a1.y}; acc1a = v2fma(s, q1a, acc1a); acc1b = v2fma(s, q1b, acc1b);
        s = (v2f){a1.z, a1.z}; acc1a = v2fma(s, q2a, acc1a); acc1b = v2fma(s, q2b, acc1b);
        s = (v2f){a1.w, a1.w}; acc1a = v2fma(s, q3a, acc1a); acc1b = v2fma(s, q3b, acc1b);
    }
    o0[0] = acc0a.x; o0[1] = acc0a.y; o0[2] = acc0b.x; o0[3] = acc0b.y;
    o1[0] = acc1a.x; o1[1] = acc1a.y; o1[2] = acc1b.x; o1[3] = acc1b.y;
}

// ---- R20 packed R17 core: per-wave tile, 4 rows x 4 cols/thread, weights
// from global/L1; unroll 2 bounds in-flight loads (full unroll = spill). ----
__device__ __forceinline__ void gemm4_pk(const float (*in)[68], const float* __restrict__ w,
                                         const float* b, int rgs, int cg,
                                         float (&out)[4][4])
{
    float bb0 = b[4*cg], bb1 = b[4*cg+1], bb2 = b[4*cg+2], bb3 = b[4*cg+3];
    v2f ba = {bb0, bb1}, bbv = {bb2, bb3};
    v2f acc[4][2];
#pragma unroll
    for (int r = 0; r < 4; r++) { acc[r][0] = ba; acc[r][1] = bbv; }
    const float* wp = w + 4 * cg;
    const int r0 = 4 * rgs;
#pragma unroll 2
    for (int i = 0; i < 64; i += 4) {
        v2f q0a = *(const v2f*)(wp + (i + 0) * 64), q0b = *(const v2f*)(wp + (i + 0) * 64 + 2);
        v2f q1a = *(const v2f*)(wp + (i + 1) * 64), q1b = *(const v2f*)(wp + (i + 1) * 64 + 2);
        v2f q2a = *(const v2f*)(wp + (i + 2) * 64), q2b = *(const v2f*)(wp + (i + 2) * 64 + 2);
        v2f q3a = *(const v2f*)(wp + (i + 3) * 64), q3b = *(const v2f*)(wp + (i + 3) * 64 + 2);
#pragma unroll
        for (int r = 0; r < 4; r++) {
            float4 a = *(const float4*)&in[r0 + r][i];
            v2f s;
            s = (v2f){a.x, a.x}; acc[r][0] = v2fma(s, q0a, acc[r][0]); acc[r][1] = v2fma(s, q0b, acc[r][1]);
            s = (v2f){a.y, a.y}; acc[r][0] = v2fma(s, q1a, acc[r][0]); acc[r][1] = v2fma(s, q1b, acc[r][1]);
            s = (v2f){a.z, a.z}; acc[r][0] = v2fma(s, q2a, acc[r][0]); acc[r][1] = v2fma(s, q2b, acc[r][1]);
            s = (v2f){a.w, a.w}; acc[r][0] = v2fma(s, q3a, acc[r][0]); acc[r][1] = v2fma(s, q3b, acc[r][1]);
        }
    }
#pragma unroll
    for (int r = 0; r < 4; r++) {
        out[r][0] = acc[r][0].x; out[r][1] = acc[r][0].y;
        out[r][2] = acc[r][1].x; out[r][3] = acc[r][1].y;
    }
}

// ---------------- CSR build: LDS-staged bucket sort (R13/R22/R23) ----------------

__global__ __launch_bounds__(256) void k_bhist(const int* __restrict__ col,
                                               int* __restrict__ bhist, int e)
{
    __shared__ int hist[256];
    int t = threadIdx.x;
    hist[t] = 0;
    __syncthreads();
    int base = blockIdx.x * SCT;
    int end = min(e, base + SCT);
    for (int i = base + t; i < end; i += 256)
        atomicAdd(&hist[col[i] >> 9], 1);
    __syncthreads();
    if (hist[t]) atomicAdd(&bhist[t], hist[t]);
}

__global__ __launch_bounds__(256) void k_bscan(const int* __restrict__ bhist,
                                               int* __restrict__ bbase, int* __restrict__ bcur)
{
    __shared__ int s[256];
    int t = threadIdx.x;
    int v = bhist[t];
    s[t] = v;
    __syncthreads();
    for (int d = 1; d < 256; d <<= 1) {
        int u = (t >= d) ? s[t - d] : 0;
        __syncthreads();
        s[t] += u;
        __syncthreads();
    }
    int b = s[t] - v;
    bbase[t] = b;
    bcur[t] = b;
}

// R23: pairs packed as u32: row in [0,17), (col&511) in [17,26).
__global__ __launch_bounds__(256) void k_bscatter2(const int* __restrict__ row,
    const int* __restrict__ col, int* __restrict__ bcur,
    unsigned* __restrict__ pairs, int e, int nbk)
{
    __shared__ int hist[256], lcur[256], gb[256], s[256];
    __shared__ unsigned buf[SCT];
    int t = threadIdx.x;
    int base = blockIdx.x * SCT;
    int end = min(e, base + SCT);
    hist[t] = 0;
    __syncthreads();
    for (int i = base + t; i < end; i += 256)
        atomicAdd(&hist[col[i] >> 9], 1);
    __syncthreads();
    int v = hist[t];
    s[t] = v;
    __syncthreads();
    for (int d = 1; d < 256; d <<= 1) {
        int u = (t >= d) ? s[t - d] : 0;
        __syncthreads();
        s[t] += u;
        __syncthreads();
    }
    lcur[t] = s[t] - v;
    __syncthreads();
    for (int i = base + t; i < end; i += 256) {
        int c = col[i];
        int slot = atomicAdd(&lcur[c >> 9], 1);
        buf[slot] = (unsigned)row[i] | ((unsigned)(c & 511) << 17);
    }
    if (v > 0) gb[t] = atomicAdd(&bcur[t], v);
    __syncthreads();
    // R22: stripe buckets across the 4 waves (disjoint buckets, read-only
    // metadata after the barrier).
    int wv = t >> 6, lane = t & 63;
    for (int b = wv; b < nbk; b += 4) {
        int cnt = hist[b];
        if (cnt == 0) continue;
        int lo = s[b] - cnt;
        int go = gb[b];
        for (int j = lane; j < cnt; j += 64)
            pairs[go + j] = buf[lo + j];
    }
}

__global__ __launch_bounds__(256) void k_fill3(const unsigned* __restrict__ pairs,
    const int* __restrict__ bbase, const int* __restrict__ bhist,
    int* __restrict__ arr, int* __restrict__ csr, int n)
{
    __shared__ int nh[512], nc[512], s[256];
    __shared__ unsigned sbuf[F3CAP];      // R23: stage packed pairs once
    int b = blockIdx.x, t = threadIdx.x;
    int pbase = bbase[b];
    int cnt = bhist[b];
    int nodebase = b << 9;
    nh[t] = 0; nh[t + 256] = 0;
    __syncthreads();
    for (int i = t; i < cnt; i += 256) {
        unsigned pv = pairs[pbase + i];
        if (i < F3CAP) sbuf[i] = pv;
        atomicAdd(&nh[pv >> 17], 1);
    }
    __syncthreads();
    int v0 = nh[2 * t], v1 = nh[2 * t + 1];
    int sum = v0 + v1;
    s[t] = sum;
    __syncthreads();
    for (int d = 1; d < 256; d <<= 1) {
        int u = (t >= d) ? s[t - d] : 0;
        __syncthreads();
        s[t] += u;
        __syncthreads();
    }
    int excl = s[t] - sum;
    int n0 = nodebase + 2 * t, n1 = n0 + 1;
    nc[2 * t]     = pbase + excl;
    nc[2 * t + 1] = pbase + excl + v0;
    if (n0 < n) arr[n0] = pbase + excl + v0;
    if (n1 < n) arr[n1] = pbase + excl + v0 + v1;
    __syncthreads();
    for (int i = t; i < cnt; i += 256) {
        unsigned pv = (i < F3CAP) ? sbuf[i] : pairs[pbase + i];
        int p = atomicAdd(&nc[pv >> 17], 1);
        csr[p] = (int)(pv & 0x1FFFFu);
    }
}

// ---------------- weight precombination ----------------
// pre layout (floats): W0[4096] | W1[4096] | c0[64]@8192 | c1[64]@8256 |
//                      u0[128]@8320 | u1[128]@8448 | v[4]@8576

__global__ __launch_bounds__(256) void k_pre(
    const float* __restrict__ wg1, const float* __restrict__ bg1,
    const float* __restrict__ wg2, const float* __restrict__ bg2,
    const float* __restrict__ wf,  const float* __restrict__ bf,
    const float* __restrict__ wc,  float* __restrict__ pre)
{
    __shared__ float wfs[4096];
    __shared__ float wcs[128];
    int t = threadIdx.x;
    for (int i = t; i < 4096; i += 256) wfs[i] = wf[i];
    if (t < 128) wcs[t] = wc[t];
    __syncthreads();
    int i = t & 63, jb = (t >> 6) * 16;
    float acc0[16], acc1[16];
#pragma unroll
    for (int j = 0; j < 16; j++) { acc0[j] = 0.f; acc1[j] = 0.f; }
#pragma unroll 1
    for (int k = 0; k < 64; k++) {
        float a = wg1[i * 64 + k];
        float b = wg2[i * 64 + k];
#pragma unroll
        for (int j = 0; j < 16; j++) {
            float w = wfs[k * 64 + jb + j];
            acc0[j] = fmaf(a, w, acc0[j]);
            acc1[j] = fmaf(b, w, acc1[j]);
        }
    }
#pragma unroll
    for (int j = 0; j < 16; j++) {
        pre[i * 64 + jb + j]        = acc0[j];
        pre[4096 + i * 64 + jb + j] = acc1[j];
    }
    if (t < 64) {
        float s0 = bf[t], s1 = bf[t];
#pragma unroll 1
        for (int m = 0; m < 64; m++) {
            s0 = fmaf(bg1[m], wfs[m * 64 + t], s0);
            s1 = fmaf(bg2[m], wfs[m * 64 + t], s1);
        }
        pre[8192 + t] = s0;
        pre[8256 + t] = s1;
        float u00 = 0.f, u01 = 0.f, u10 = 0.f, u11 = 0.f;
#pragma unroll 1
        for (int m = 0; m < 64; m++) {
            float g1 = wg1[t * 64 + m], g2 = wg2[t * 64 + m];
            u00 = fmaf(g1, wcs[m * 2 + 0], u00);
            u01 = fmaf(g1, wcs[m * 2 + 1], u01);
            u10 = fmaf(g2, wcs[m * 2 + 0], u10);
            u11 = fmaf(g2, wcs[m * 2 + 1], u11);
        }
        pre[8320 + t * 2]     = u00;
        pre[8320 + t * 2 + 1] = u01;
        pre[8448 + t * 2]     = u10;
        pre[8448 + t * 2 + 1] = u11;
    }
    if (t == 0) {
        float v00 = 0.f, v01 = 0.f, v10 = 0.f, v11 = 0.f;
#pragma unroll 1
        for (int m = 0; m < 64; m++) {
            v00 = fmaf(bg1[m], wcs[m * 2 + 0], v00);
            v01 = fmaf(bg1[m], wcs[m * 2 + 1], v01);
            v10 = fmaf(bg2[m], wcs[m * 2 + 0], v10);
            v11 = fmaf(bg2[m], wcs[m * 2 + 1], v11);
        }
        pre[8576] = v00; pre[8577] = v01; pre[8578] = v10; pre[8579] = v11;
    }
}

// ---------------- node MLP: per-wave 16-row tile, barrier-free (R17, packed R20) ----------------

__global__ __launch_bounds__(256) void k_mlp(const float* __restrict__ x,
    const float* __restrict__ w1, const float* __restrict__ b1,
    const float* __restrict__ w2, const float* __restrict__ b2,
    const float* __restrict__ w3, const float* __restrict__ b3,
    const int* __restrict__ arr, float* __restrict__ h,
    float2* __restrict__ nrm2, int n)
{
    __shared__ float b1s[64], b2s[64], b3s[64];
    __shared__ float xs[4][16][68];          // one 16-row slice per wave
    int t = threadIdx.x;
    if (t < 64) { b1s[t] = b1[t]; b2s[t] = b2[t]; b3s[t] = b3[t]; }
    __syncthreads();                          // once, for biases only
    int wv = t >> 6, lane = t & 63;
    int cg = lane & 15, rgs = lane >> 4;      // thread: rows 4*rgs..+3, cols 4*cg..+3
    int row0 = blockIdx.x * 64 + wv * 16;     // this wave's 16 rows
    float (*ws)[68] = xs[wv];

    // stage: lane stages row lane>>2, cols (lane&3)*16 (wave reads 4KB contiguous)
    {
        int r = lane >> 2, c = (lane & 3) * 16;
        int grow = row0 + r;
        float4 v0 = make_float4(0.f,0.f,0.f,0.f), v1 = v0, v2 = v0, v3 = v0;
        if (grow < n) {
            const float* p = x + (size_t)grow * 64 + c;
            v0 = *(const float4*)p;       v1 = *(const float4*)(p + 4);
            v2 = *(const float4*)(p + 8); v3 = *(const float4*)(p + 12);
        }
        *(float4*)&ws[r][c]      = v0; *(float4*)&ws[r][c + 4]  = v1;
        *(float4*)&ws[r][c + 8]  = v2; *(float4*)&ws[r][c + 12] = v3;
    }
    lds_fence();

    float acc[4][4];
    // layer 1: read xs slice, relu, overwrite in place (lockstep: all wave
    // reads precede the write instructions; fences order DS completion)
    gemm4_pk(ws, w1, b1s, rgs, cg, acc);
    lds_fence();
#pragma unroll
    for (int r = 0; r < 4; r++)
        *(float4*)&ws[4 * rgs + r][4 * cg] =
            make_float4(fmaxf(acc[r][0], 0.f), fmaxf(acc[r][1], 0.f),
                        fmaxf(acc[r][2], 0.f), fmaxf(acc[r][3], 0.f));
    lds_fence();
    // layer 2
    gemm4_pk(ws, w2, b2s, rgs, cg, acc);
    lds_fence();
#pragma unroll
    for (int r = 0; r < 4; r++)
        *(float4*)&ws[4 * rgs + r][4 * cg] =
            make_float4(fmaxf(acc[r][0], 0.f), fmaxf(acc[r][1], 0.f),
                        fmaxf(acc[r][2], 0.f), fmaxf(acc[r][3], 0.f));
    lds_fence();
    // layer 3 + fused per-node scalars
    gemm4_pk(ws, w3, b3s, rgs, cg, acc);

    int r0g = row0 + 4 * rgs;
    float sr[4];
#pragma unroll
    for (int r = 0; r < 4; r++) {
        int grow = r0g + r;
        if (grow < n)
            *(float4*)&h[(size_t)grow * 64 + 4 * cg] =
                make_float4(acc[r][0], acc[r][1], acc[r][2], acc[r][3]);
        sr[r] = acc[r][0]*acc[r][0] + acc[r][1]*acc[r][1]
              + acc[r][2]*acc[r][2] + acc[r][3]*acc[r][3];
    }
#pragma unroll
    for (int d = 1; d < 16; d <<= 1) {
#pragma unroll
        for (int r = 0; r < 4; r++) sr[r] += __shfl_xor(sr[r], d, 64);
    }
    if (cg == 0) {
#pragma unroll
        for (int r = 0; r < 4; r++) {
            int grow = r0g + r;
            if (grow < n) {
                int st = (grow == 0) ? 0 : arr[grow - 1];
                nrm2[grow] = make_float2(1.0f / (sqrtf(sr[r]) + 1e-12f),
                                         rsqrtf((float)(arr[grow] - st + 1)));
            }
        }
    }
}

// ---------------- edge pass: 2 nodes/wave, per half 4 edge-groups x 8 lanes (R18/R20) ----------------

__global__ __launch_bounds__(256) void k_gather(const float* __restrict__ h,
    const int* __restrict__ arr, const int* __restrict__ csr,
    const float2* __restrict__ nrm2, const float* __restrict__ beta_p,
    const float* __restrict__ wc,
    float* __restrict__ agg, float2* __restrict__ yp, int n)
{
    // [wave][g][sub][col+pad]: pad 66 -> write banks (4g+2sub+8s)%32 cover
    // all 32 banks at 8 words/bank (floor). 16.9KB total.
    __shared__ float reda[4][4][2][66];
    __shared__ float redn[4][4][2][66];
    int wv = threadIdx.x >> 6;
    int lane = threadIdx.x & 63;
    int sub = lane >> 5;              // which node in this wave
    int l32 = lane & 31;              // lane within half
    int g = l32 >> 3, s = l32 & 7;    // 4 groups x 8 lanes per half
    int base = sub << 5;              // absolute lane offset of this half
    int node = blockIdx.x * 8 + wv * 2 + sub;
    bool valid = node < n;
    int nd = valid ? node : 0;
    float beta = beta_p[0];
    const char* hb = (const char*)h;

    // self row: lane covers cols 8s..8s+7 (32-bit byte offset -> SADDR loads)
    unsigned selfoff = ((unsigned)nd << 8) + ((unsigned)s << 5);
    float4 hA = *(const float4*)(hb + selfoff);
    float4 hB = *(const float4*)(hb + selfoff + 16);
    v2f hc0 = {hA.x, hA.y}, hc1 = {hA.z, hA.w};
    v2f hc2 = {hB.x, hB.y}, hc3 = {hB.z, hB.w};

    v2f sv = hc0 * hc0;
    sv = v2fma(hc1, hc1, sv); sv = v2fma(hc2, hc2, sv); sv = v2fma(hc3, hc3, sv);
    float ss = sv.x + sv.y;
#pragma unroll
    for (int d = 1; d < 8; d <<= 1) ss += __shfl_xor(ss, d, 64);   // within group
    float2 ncv = nrm2[nd];
    float rnc = ncv.x, dc = ncv.y;
    float brn = beta * rnc;                 // hoisted: w = exp(brn * p * rnr)
    float wself = __expf(brn * ss * rnc);

    v2f a0 = {0.f,0.f}, a1 = {0.f,0.f}, a2 = {0.f,0.f}, a3 = {0.f,0.f};
    v2f n0 = {0.f,0.f}, n1 = {0.f,0.f}, n2 = {0.f,0.f}, n3 = {0.f,0.f};
    float denom = 0.f;
    if (g == 0) {                           // self-loop contribution, once per half
        v2f dcv = {dc, dc}, wsv = {wself, wself};
        a0 = dcv * hc0; a1 = dcv * hc1; a2 = dcv * hc2; a3 = dcv * hc3;
        n0 = wsv * hc0; n1 = wsv * hc1; n2 = wsv * hc2; n3 = wsv * hc3;
        denom = wself;
    }

    int start = (!valid || nd == 0) ? 0 : arr[nd - 1];
    int end = valid ? arr[nd] : 0;
#pragma unroll 1
    for (int k0 = start; k0 < end; k0 += 32) {
        int m = min(32, end - k0);
        int idx = 0; float rv = 0.f, dv = 0.f;
        if (l32 < m) {
            idx = csr[k0 + l32];
            float2 ndv = nrm2[idx];
            rv = ndv.x; dv = ndv.y;
        }
        int ei = __shfl(idx, base + g, 64);
        unsigned eoff = ((unsigned)ei << 8) + ((unsigned)s << 5);
        float4 cA = *(const float4*)(hb + eoff);
        float4 cB = *(const float4*)(hb + eoff + 16);
#pragma unroll 1
        for (int k = 0; k < m; k += 4) {
            float4 fA = cA, fB = cB;
            if (k + 4 < m) {
                int e2 = __shfl(idx, base + k + 4 + g, 64);
                unsigned off2 = ((unsigned)e2 << 8) + ((unsigned)s << 5);
                cA = *(const float4*)(hb + off2);
                cB = *(const float4*)(hb + off2 + 16);
            }
            float rnr = __shfl(rv, base + k + g, 64);
            float dvr = __shfl(dv, base + k + g, 64);
            v2f f0 = {fA.x, fA.y}, f1 = {fA.z, fA.w};
            v2f f2 = {fB.x, fB.y}, f3 = {fB.z, fB.w};
            // dot(h[src], h[dst]) over this lane's 8 cols, packed
            v2f ps = f0 * hc0;
            ps = v2fma(f1, hc1, ps); ps = v2fma(f2, hc2, ps); ps = v2fma(f3, hc3, ps);
            float p = ps.x + ps.y;
#pragma unroll
            for (int d = 1; d < 8; d <<= 1) p += __shfl_xor(p, d, 64);
            bool act = (k + g) < m;
            float w   = act ? __expf(brn * p * rnr) : 0.f;
            float dve = act ? dvr : 0.f;
            v2f wsp = {w, w}, dsp = {dve, dve};
            a0 = v2fma(dsp, f0, a0); a1 = v2fma(dsp, f1, a1);
            a2 = v2fma(dsp, f2, a2); a3 = v2fma(dsp, f3, a3);
            n0 = v2fma(wsp, f0, n0); n1 = v2fma(wsp, f1, n1);
            n2 = v2fma(wsp, f2, n2); n3 = v2fma(wsp, f3, n3);
            denom += w;
        }
    }

    // ---- cross-group reduce via padded LDS transpose ----
    {
        float* wa = &reda[wv][g][sub][8 * s];
        float* wn = &redn[wv][g][sub][8 * s];
        *(float4*)wa       = make_float4(a0.x, a0.y, a1.x, a1.y);
        *(float4*)(wa + 4) = make_float4(a2.x, a2.y, a3.x, a3.y);
        *(float4*)wn       = make_float4(n0.x, n0.y, n1.x, n1.y);
        *(float4*)(wn + 4) = make_float4(n2.x, n2.y, n3.x, n3.y);
    }
    lds_fence();
    // lane (sub,l32) sums cols l32 and l32+32 of its node across the 4 groups
    float a_lo, a_hi, n_lo, n_hi;
    {
        const float* r0p = &reda[wv][0][sub][0];
        const float* r1p = &redn[wv][0][sub][0];
        float t0 = r0p[l32]       + r0p[132 + l32];
        float t1 = r0p[264 + l32] + r0p[396 + l32];
        float t2 = r0p[l32 + 32]       + r0p[132 + l32 + 32];
        float t3 = r0p[264 + l32 + 32] + r0p[396 + l32 + 32];
        a_lo = t0 + t1; a_hi = t2 + t3;
        float u0 = r1p[l32]       + r1p[132 + l32];
        float u1 = r1p[264 + l32] + r1p[396 + l32];
        float u2 = r1p[l32 + 32]       + r1p[132 + l32 + 32];
        float u3 = r1p[264 + l32 + 32] + r1p[396 + l32 + 32];
        n_lo = u0 + u1; n_hi = u2 + u3;
    }
    if (valid) {
        agg[(size_t)node * 64 + l32]      = dc * a_lo;
        agg[(size_t)node * 64 + l32 + 32] = dc * a_hi;
    }

    // denom varies only across g within the half: 2-stage reduce
    denom += __shfl_xor(denom, 8, 64);
    denom += __shfl_xor(denom, 16, 64);

    // classifier contribution of h1: lane owns cols l32 and l32+32
    float2 w_lo = *(const float2*)(wc + 128 + 2 * l32);
    float2 w_hi = *(const float2*)(wc + 128 + 2 * (l32 + 32));
    float cx = n_lo * w_lo.x + n_hi * w_hi.x;
    float cy = n_lo * w_lo.y + n_hi * w_hi.y;
#pragma unroll
    for (int d = 1; d < 32; d <<= 1) { cx += __shfl_xor(cx, d, 64); cy += __shfl_xor(cy, d, 64); }
    if (l32 == 0 && valid) {
        float inv = 1.0f / denom;
        yp[node] = make_float2(cx * inv, cy * inv);
    }
}

// ---------------- epilogue: LDS weights + multi-tile loop (R18 structure, packed R20) ----------------

__global__ __launch_bounds__(256) void k_epi(const float* __restrict__ agg,
    const float* __restrict__ hbuf, const float2* __restrict__ yp,
    const float* __restrict__ pre, const float* __restrict__ wx,
    const float* __restrict__ bx, const float* __restrict__ bc,
    float* __restrict__ y, int n, int ntiles)
{
    __shared__ float W0s[4096], W1s[4096], wxs[4096];
    __shared__ float c0s[64], c1s[64], bxs[64], us[256], vs[4], bcs[2];
    __shared__ float A[32][68], H[32][68];
    int t = threadIdx.x;
    for (int i = t; i < 4096; i += 256) { W0s[i] = pre[i]; W1s[i] = pre[4096 + i]; wxs[i] = wx[i]; }
    if (t < 64) { c0s[t] = pre[8192 + t]; c1s[t] = pre[8256 + t]; bxs[t] = bx[t]; }
    us[t] = pre[8320 + t];
    if (t < 4) vs[t] = pre[8576 + t];
    if (t < 2) bcs[t] = bc[t];
    __syncthreads();
    int cg = t & 15, rg = t >> 4;
    for (int tile = blockIdx.x; tile < ntiles; tile += gridDim.x) {
        int row0 = tile * 32;
        load_rows32(agg,  row0, n, A, t);
        load_rows32(hbuf, row0, n, H, t);
        __syncthreads();
        int r0g = row0 + 2 * rg, r1g = r0g + 1;
        float xp0[4], xp1[4];
        gemm_core_pk(H, wxs, bxs, rg, cg, xp0, xp1);
#pragma unroll
        for (int j = 0; j < 4; j++) { xp0[j] = fast_tanh(xp0[j]); xp1[j] = fast_tanh(xp1[j]); }
        float a0[4], a1[4];
        gemm_core_pk(A, W0s, c0s, rg, cg, a0, a1);
        float l00 = 0.f, l01 = 0.f;
#pragma unroll
        for (int j = 0; j < 4; j++) {
            l00 = fmaf(fast_tanh(a0[j]), xp0[j], l00);
            l01 = fmaf(fast_tanh(a1[j]), xp1[j], l01);
        }
        gemm_core_pk(A, W1s, c1s, rg, cg, a0, a1);
        float l10 = 0.f, l11 = 0.f;
#pragma unroll
        for (int j = 0; j < 4; j++) {
            l10 = fmaf(fast_tanh(a0[j]), xp0[j], l10);
            l11 = fmaf(fast_tanh(a1[j]), xp1[j], l11);
        }
        float4 av0 = *(const float4*)&A[2 * rg][4 * cg];
        float4 av1 = *(const float4*)&A[2 * rg + 1][4 * cg];
        float za0=0.f, za1=0.f, zb0=0.f, zb1=0.f;
        float zc0=0.f, zc1=0.f, zd0=0.f, zd1=0.f;
#pragma unroll
        for (int j = 0; j < 4; j++) {
            int k = 4 * cg + j;
            float u0c0 = us[k * 2], u0c1 = us[k * 2 + 1];
            float u1c0 = us[128 + k * 2], u1c1 = us[128 + k * 2 + 1];
            float p0 = (&av0.x)[j], p1 = (&av1.x)[j];
            za0 = fmaf(p0, u0c0, za0); za1 = fmaf(p0, u0c1, za1);
            zb0 = fmaf(p0, u1c0, zb0); zb1 = fmaf(p0, u1c1, zb1);
            zc0 = fmaf(p1, u0c0, zc0); zc1 = fmaf(p1, u0c1, zc1);
            zd0 = fmaf(p1, u1c0, zd0); zd1 = fmaf(p1, u1c1, zd1);
        }
#pragma unroll
        for (int d = 1; d < 16; d <<= 1) {
            l00 += __shfl_xor(l00, d, 64); l01 += __shfl_xor(l01, d, 64);
            l10 += __shfl_xor(l10, d, 64); l11 += __shfl_xor(l11, d, 64);
            za0 += __shfl_xor(za0, d, 64); za1 += __shfl_xor(za1, d, 64);
            zb0 += __shfl_xor(zb0, d, 64); zb1 += __shfl_xor(zb1, d, 64);
            zc0 += __shfl_xor(zc0, d, 64); zc1 += __shfl_xor(zc1, d, 64);
            zd0 += __shfl_xor(zd0, d, 64); zd1 += __shfl_xor(zd1, d, 64);
        }
        if (cg == 0) {
            if (r0g < n) {
                float mx = fmaxf(l00, l10);
                float e0 = __expf(l00 - mx), e1 = __expf(l10 - mx);
                float inv = 1.0f / (e0 + e1);
                float s0 = e0 * inv, s1 = e1 * inv;
                float2 ypv = yp[r0g];
                float y0v = s0 * (za0 + vs[0]) + s1 * (zb0 + vs[2]) + ypv.x + bcs[0];
                float y1v = s0 * (za1 + vs[1]) + s1 * (zb1 + vs[3]) + ypv.y + bcs[1];
                *(float2*)&y[(size_t)r0g * 2] = make_float2(y0v, y1v);
            }
            if (r1g < n) {
                float mx = fmaxf(l01, l11);
                float e0 = __expf(l01 - mx), e1 = __expf(l11 - mx);
                float inv = 1.0f / (e0 + e1);
                float s0 = e0 * inv, s1 = e1 * inv;
                float2 ypv = yp[r1g];
                float y0v = s0 * (zc0 + vs[0]) + s1 * (zd0 + vs[2]) + ypv.x + bcs[0];
                float y1v = s0 * (zc1 + vs[1]) + s1 * (zd1 + vs[3]) + ypv.y + bcs[1];
                *(float2*)&y[(size_t)r1g * 2] = make_float2(y0v, y1v);
            }
        }
        __syncthreads();
    }
}

extern "C" void kernel_launch(void* const* d_in, const int* in_sizes, int n_in,
                              void* d_out, int out_size, void* d_ws, size_t ws_size,
                              hipStream_t stream)
{
    const float* x    = (const float*)d_in[0];
    const int*   ei   = (const int*)d_in[1];
    const float* w1   = (const float*)d_in[2];
    const float* b1   = (const float*)d_in[3];
    const float* w2   = (const float*)d_in[4];
    const float* b2   = (const float*)d_in[5];
    const float* w3   = (const float*)d_in[6];
    const float* b3   = (const float*)d_in[7];
    const float* wg1  = (const float*)d_in[8];
    const float* bg1  = (const float*)d_in[9];
    const float* wg2  = (const float*)d_in[10];
    const float* bg2  = (const float*)d_in[11];
    const float* beta = (const float*)d_in[12];
    const float* wf   = (const float*)d_in[13];
    const float* bf   = (const float*)d_in[14];
    const float* wx   = (const float*)d_in[15];
    const float* bx   = (const float*)d_in[16];
    const float* wc   = (const float*)d_in[17];
    const float* bc   = (const float*)d_in[18];
    float* y = (float*)d_out;

    int n = in_sizes[0] / 64;     // 100000
    int e = in_sizes[1] / 2;      // 1600000
    const int* row = ei;
    const int* col = ei + e;

    // workspace ~34MB
    char* p = (char*)d_ws;
    auto alloc = [&](size_t bytes) { char* q = p; p += (bytes + 255) & ~(size_t)255; return q; };
    float*  h    = (float*)alloc((size_t)n * 64 * 4);    // 25.6MB (pairs -> h)
    int*    csr  = (int*)alloc((size_t)e * 4);           // 6.4MB
    float2* nrm2 = (float2*)alloc((size_t)n * 8);        // 0.8MB
    int*    arr  = (int*)alloc((size_t)(n + 1) * 4);     // 0.4MB
    float2* yp   = (float2*)alloc((size_t)n * 8);        // 0.8MB
    float*  pre  = (float*)alloc(8704 * 4);              // combined weights
    int*    bhist = (int*)alloc(256 * 4);
    int*    bbase = (int*)alloc(256 * 4);
    int*    bcur  = (int*)alloc(256 * 4);

    // packed pairs buffer (6.4MB) aliases h: consumed by k_fill3 before
    // k_mlp writes h.
    unsigned* pairs = (unsigned*)h;
    // agg reuses x's buffer (x dead after k_mlp; harness restores d_in).
    float* agg = (float*)d_in[0];

    int ntiles = (n + 31) / 32;            // 3125 32-row tiles (k_epi)
    int ntile64 = (n + 63) / 64;           // 1563 64-row tiles (k_mlp)
    int nbk = (n + 511) >> 9;              // 196 buckets (col>>9)
    int nsct = (e + SCT - 1) / SCT;        // 256 scatter tiles (R23)

    k_pre<<<1, 256, 0, stream>>>(wg1, bg1, wg2, bg2, wf, bf, wc, pre);
    hipMemsetAsync(bhist, 0, 256 * sizeof(int), stream);
    k_bhist<<<nsct, 256, 0, stream>>>(col, bhist, e);
    k_bscan<<<1, 256, 0, stream>>>(bhist, bbase, bcur);
    k_bscatter2<<<nsct, 256, 0, stream>>>(row, col, bcur, pairs, e, nbk);
    k_fill3<<<nbk, 256, 0, stream>>>(pairs, bbase, bhist, arr, csr, n);
    k_mlp<<<ntile64, 256, 0, stream>>>(x, w1, b1, w2, b2, w3, b3, arr, h, nrm2, n);
    k_gather<<<(n + 7) / 8, 256, 0, stream>>>(h, arr, csr, nrm2, beta, wc, agg, yp, n);
    k_epi<<<1024, 256, 0, stream>>>(agg, h, yp, pre, wx, bx, bc, y, n, ntiles);
}